// Round 8
// baseline (714.657 us; speedup 1.0000x reference)
//
#include <hip/hip_runtime.h>
#include <hip/hip_bf16.h>

#define BN_EPS 1e-5f

typedef __attribute__((ext_vector_type(8))) short bf16x8;
typedef __attribute__((ext_vector_type(4))) float f32x4;
typedef unsigned short u16;
typedef unsigned int u32;

__device__ __forceinline__ void load16(const void* g, void* l) {
    __builtin_amdgcn_global_load_lds((const __attribute__((address_space(1))) void*)g,
                                     (__attribute__((address_space(3))) void*)l, 16, 0, 0);
}
__device__ __forceinline__ u16 f2b(float v) {
    __hip_bfloat16 h = __float2bfloat16(v);
    return *reinterpret_cast<u16*>(&h);
}
__device__ __forceinline__ float ternq(float x, float d) {
    return (fabsf(x) > d) ? (x > 0.f ? 1.f : -1.f) : 0.f;
}

// ---------------- ws layout (BYTE offsets) ----------------
constexpr size_t ALGN(size_t x) { return (x + 255) & ~(size_t)255; }
constexpr size_t O_SUMS = 0;                                   // 8 f32
constexpr size_t O_W1R  = 256;                                 // 288 f32
constexpr size_t O_WF2Q = ALGN(O_W1R + 288 * 4);               // 32768 f32
constexpr size_t O_WF3Q = ALGN(O_WF2Q + 32768 * 4);            // 1280 f32
constexpr size_t O_BQ2  = ALGN(O_WF3Q + 1280 * 4);             // [64][288] bf16 (frag layout)
constexpr size_t O_BQ3  = ALGN(O_BQ2 + 64 * 288 * 2);          // B3' primed [18][8][64][8] bf16
constexpr size_t O_BQ4  = ALGN(O_BQ3 + 128 * 576 * 2);         // B4' primed [36][8][64][8] bf16
constexpr size_t O_BQF1 = ALGN(O_BQ4 + 128 * 1152 * 2);        // [256][6272] bf16
constexpr size_t O_F1   = ALGN(O_BQF1 + (size_t)256 * 6272 * 2);  // [1024][256] f32
constexpr size_t O_F2   = ALGN(O_F1 + 1024 * 256 * 4);         // [1024][128] f32
constexpr size_t O_ACT1 = ALGN(O_F2 + 1024 * 128 * 4);         // pad30 C=32 bf16
constexpr size_t O_ACT2 = ALGN(O_ACT1 + (size_t)1024 * 900 * 32 * 2);  // pad16 C=64
constexpr size_t O_ACT3 = ALGN(O_ACT2 + (size_t)1024 * 256 * 64 * 2);  // (unused)
constexpr size_t O_ACT4 = ALGN(O_ACT3 + (size_t)1024 * 256 * 128 * 2); // [1024*49][128]

// ---------------- ternarization (merged) ----------------
__global__ void zero_sums(float* s) { if (threadIdx.x < 8) s[threadIdx.x] = 0.f; }

__device__ void absmean_seg(const float* __restrict__ w, int n4, float* __restrict__ sum,
                            int b0, int nb) {
    __shared__ float sm[256];
    float s = 0.f;
    for (int i = b0 * 256 + threadIdx.x; i < n4; i += nb * 256) {
        float4 v = ((const float4*)w)[i];
        s += fabsf(v.x) + fabsf(v.y) + fabsf(v.z) + fabsf(v.w);
    }
    sm[threadIdx.x] = s;
    __syncthreads();
    for (int o = 128; o > 0; o >>= 1) {
        if (threadIdx.x < o) sm[threadIdx.x] += sm[threadIdx.x + o];
        __syncthreads();
    }
    if (threadIdx.x == 0) atomicAdd(sum, sm[0]);
}

__global__ void absmean_all(const float* w1, const float* w2, const float* w3, const float* w4,
                            const float* wf1, const float* wf2, const float* wf3, float* sums) {
    int b = blockIdx.x;
    if (b < 160)      absmean_seg(wf1, 401408, sums + 4, b, 160);
    else if (b < 192) absmean_seg(w4, 36864, sums + 3, b - 160, 32);
    else if (b < 208) absmean_seg(w3, 18432, sums + 2, b - 192, 16);
    else if (b < 216) absmean_seg(w2, 4608, sums + 1, b - 208, 8);
    else if (b < 224) absmean_seg(wf2, 8192, sums + 5, b - 216, 8);
    else if (b < 225) absmean_seg(w1, 72, sums + 0, 0, 1);
    else              absmean_seg(wf3, 320, sums + 6, 0, 1);
}

// conv2 weights: src [co][ci][9] -> frag layout [co][tap*CIN+ci]
__device__ void tern_conv_seg(const float* __restrict__ w, float d, u16* __restrict__ bq,
                              int COUT, int CIN, int b0, int nb) {
    int N = COUT * CIN * 9;
    for (int i = b0 * 256 + threadIdx.x; i < N; i += nb * 256) {
        float q = ternq(w[i], d);
        int co = i / (CIN * 9), r = i % (CIN * 9);
        int ci = r / 9, tap = r % 9;
        bq[(size_t)co * CIN * 9 + tap * CIN + ci] = f2b(q);
    }
}
// conv3/4 weights -> primed coalesced layout [s][nt][lane][8] (COUT=128)
__device__ void tern_conv_prime_seg(const float* __restrict__ w, float d, u16* __restrict__ bqp,
                                    int CIN, int b0, int nb) {
    int N = 128 * CIN * 9;
    for (int i = b0 * 256 + threadIdx.x; i < N; i += nb * 256) {
        float q = ternq(w[i], d);
        int co = i / (CIN * 9), r = i % (CIN * 9);
        int ci = r / 9, tap = r % 9;
        int k = tap * CIN + ci;
        int s = k >> 5, qd = (k & 31) >> 3, e = k & 7;
        int lane = qd * 16 + (co & 15), nt = co >> 4;
        bqp[((size_t)(s * 8 + nt) * 64 + lane) * 8 + e] = f2b(q);
    }
}
__device__ void tern_f32_seg(const float* __restrict__ w, float d, float* __restrict__ wq,
                             int N, int b0, int nb) {
    for (int i = b0 * 256 + threadIdx.x; i < N; i += nb * 256) wq[i] = ternq(w[i], d);
}

__global__ void tern_all(const float* w1, const float* w2, const float* w3, const float* w4,
                         const float* wf1, const float* wf2, const float* wf3,
                         const float* __restrict__ sums,
                         float* w1r, u16* bq2, u16* bq3p, u16* bq4p, u16* bqf1,
                         float* wf2q, float* wf3q) {
    int b = blockIdx.x;
    if (b < 1) {
        tern_f32_seg(w1, 0.7f * sums[0] / 288.f, w1r, 288, 0, 1);
    } else if (b < 9) {
        tern_conv_seg(w2, 0.7f * sums[1] / 18432.f, bq2, 64, 32, b - 1, 8);
    } else if (b < 41) {
        tern_conv_prime_seg(w3, 0.7f * sums[2] / 73728.f, bq3p, 64, b - 9, 32);
    } else if (b < 105) {
        tern_conv_prime_seg(w4, 0.7f * sums[3] / 147456.f, bq4p, 128, b - 41, 64);
    } else if (b < 617) {
        // wf1 [256][6272], k=c*49+s -> bf16 [256][s*128+c]
        float d = 0.7f * sums[4] / 1605632.f;
        for (int i = (b - 105) * 256 + threadIdx.x; i < 1605632; i += 512 * 256) {
            float q = ternq(wf1[i], d);
            int j = i / 6272, k = i % 6272;
            int c = k / 49, s = k % 49;
            bqf1[(size_t)j * 6272 + s * 128 + c] = f2b(q);
        }
    } else if (b < 633) {
        tern_f32_seg(wf2, 0.7f * sums[5] / 32768.f, wf2q, 32768, b - 617, 16);
    } else {
        tern_f32_seg(wf3, 0.7f * sums[6] / 1280.f, wf3q, 1280, 0, 1);
    }
}

__global__ void zero_f1(float* f1) {
    ((float4*)f1)[blockIdx.x * 256 + threadIdx.x] = make_float4(0.f, 0.f, 0.f, 0.f);
}

// ---------------- conv1 direct (Cin=1) -> pad30 NHWC bf16 ----------------
__global__ __launch_bounds__(256)
void conv1_direct(const float* __restrict__ x, const float* __restrict__ w1r,
                  const float* __restrict__ bias, const float* __restrict__ gam,
                  const float* __restrict__ bet, const float* __restrict__ mu,
                  const float* __restrict__ var, u16* __restrict__ out) {
    __shared__ float xs[784];
    __shared__ float wsh[288];
    __shared__ float scl[32], sft[32];
    const int n = blockIdx.x, tid = threadIdx.x;
    for (int i = tid; i < 784; i += 256) xs[i] = x[(size_t)n * 784 + i];
    for (int i = tid; i < 288; i += 256) wsh[i] = w1r[i];
    if (tid < 32) {
        float s = gam[tid] * rsqrtf(var[tid] + BN_EPS);
        scl[tid] = s;
        sft[tid] = (bias[tid] - mu[tid]) * s + bet[tid];
    }
    __syncthreads();
    for (int p = tid; p < 784; p += 256) {
        int y = p / 28, xx = p % 28;
        float patch[9];
#pragma unroll
        for (int dy = 0; dy < 3; ++dy)
#pragma unroll
            for (int dx = 0; dx < 3; ++dx) {
                int gy = y + dy - 1, gx = xx + dx - 1;
                patch[dy * 3 + dx] = (gy >= 0 && gy < 28 && gx >= 0 && gx < 28) ? xs[gy * 28 + gx] : 0.f;
            }
        u32 pk[16];
#pragma unroll
        for (int co = 0; co < 32; co += 2) {
            float s0 = 0.f, s1 = 0.f;
#pragma unroll
            for (int t = 0; t < 9; ++t) {
                s0 += wsh[co * 9 + t] * patch[t];
                s1 += wsh[(co + 1) * 9 + t] * patch[t];
            }
            float v0 = fmaxf(s0 * scl[co] + sft[co], 0.f);
            float v1 = fmaxf(s1 * scl[co + 1] + sft[co + 1], 0.f);
            pk[co >> 1] = ((u32)f2b(v1) << 16) | (u32)f2b(v0);
        }
        size_t base = ((size_t)(n * 30 + y + 1) * 30 + (xx + 1)) * 32;
#pragma unroll
        for (int q = 0; q < 4; ++q) ((uint4*)(out + base))[q] = ((uint4*)pk)[q];
    }
}

// ---------------- border zero for padded NHWC buffers ----------------
template<int C, int HP, int HV>
__global__ void border_zero(u16* __restrict__ buf) {
    constexpr int NB = 2 * HP + 2 * HV;
    constexpr int CG = C / 8;
    int i = blockIdx.x * blockDim.x + threadIdx.x;
    if (i >= 1024 * NB * CG) return;
    int cg = i % CG, r = i / CG;
    int b = r % NB, n = r / NB;
    int py, px;
    if (b < HP)               { py = 0;                  px = b; }
    else if (b < 2 * HP)      { py = HP - 1;             px = b - HP; }
    else if (b < 2 * HP + HV) { py = b - 2 * HP + 1;     px = 0; }
    else                      { py = b - 2 * HP - HV + 1; px = HP - 1; }
    size_t off = ((size_t)(n * HP + py) * HP + px) * C + cg * 8;
    *(uint4*)(buf + off) = make_uint4(0, 0, 0, 0);
}

// ---------------- conv2: R3-style implicit GEMM, frag-major LDS, fused pool ----------------
template<int CIN, int BN, int HV, int HP, int G, bool POOL, bool PADOUT>
__global__ __launch_bounds__(256)
void convgemm(const u16* __restrict__ act, const u16* __restrict__ bq,
              const float* __restrict__ bias, const float* __restrict__ gam,
              const float* __restrict__ bet, const float* __restrict__ mu,
              const float* __restrict__ var, u16* __restrict__ out) {
    constexpr int BM = 128;
    constexpr int K = 9 * CIN;
    constexpr int S = K / (32 * G);
    constexpr int TPC = CIN / 32;
    constexpr int NT = BN / 32;
    constexpr int RB = BN / 64;
    constexpr int HO = HV / 2;
    constexpr int PP = POOL ? HO * HO : HV * HV;

    __shared__ __align__(16) u16 Alds[G][BM * 32];
    __shared__ __align__(16) u16 Blds[G][BN * 32];
    __shared__ int rowA[BM];
    __shared__ int rowO[BM];
    __shared__ float scl[BN], sft[BN];

    const int tid = threadIdx.x;
    const int m0 = blockIdx.x * BM;

    for (int t = tid; t < BM; t += 256) {
        int base;
        if (POOL) {
            int p = (m0 >> 2) + (t >> 2), q = t & 3;
            int n = p / PP, rr = p % PP;
            int oy = rr / HO, ox = rr % HO;
            int y = oy * 2 + (q >> 1), x = ox * 2 + (q & 1);
            base = ((n * HP + y) * HP + x) * CIN;
        } else {
            int m = m0 + t;
            int n = m / PP, rr = m % PP;
            int y = rr / HV, x = rr % HV;
            base = ((n * HP + y) * HP + x) * CIN;
        }
        rowA[t] = base;
    }
    if (POOL) {
        if (tid < 32) {
            int p = (m0 >> 2) + tid;
            int n = p / PP, rr = p % PP;
            int oy = rr / HO, ox = rr % HO;
            rowO[tid] = PADOUT ? ((n * 16 + oy + 1) * 16 + ox + 1) * BN : p * BN;
        }
    } else {
        for (int t = tid; t < BM; t += 256) {
            int m = m0 + t;
            int n = m / PP, rr = m % PP;
            int y = rr / HV, x = rr % HV;
            rowO[t] = PADOUT ? ((n * 16 + y + 1) * 16 + x + 1) * BN : m * BN;
        }
    }
    if (tid < BN) {
        float s = gam[tid] * rsqrtf(var[tid] + BN_EPS);
        scl[tid] = s;
        sft[tid] = (bias[tid] - mu[tid]) * s + bet[tid];
    }
    __syncthreads();

    int arow[2];
    arow[0] = rowA[(tid >> 6) * 16 + (tid & 15)];
    arow[1] = rowA[64 + (tid >> 6) * 16 + (tid & 15)];
    const int chunkb = ((tid >> 4) & 3) * 16;
    const int bco = (tid >> 6) * 16 + (tid & 15);
    const char* actb = (const char*)act;
    const char* bqb  = (const char*)bq;

    const int wave = tid >> 6, lane = tid & 63;
    const int wm = wave & 1, wn = wave >> 1;
    const int fr16 = lane * 16;

    f32x4 acc[4][NT] = {};

    for (int s = 0; s < S; ++s) {
#pragma unroll
        for (int j = 0; j < G; ++j) {
            int g = s * G + j;
            int tap = g / TPC, cio = (g % TPC) * 32;
            int dy = tap / 3, dx = tap % 3;
            int toffb = ((dy * HP + dx) * CIN + cio) * 2;
            char* Al = (char*)Alds[j];
#pragma unroll
            for (int r = 0; r < 2; ++r)
                load16(actb + (size_t)arow[r] * 2 + toffb + chunkb, Al + r * 4096 + tid * 16);
            char* Bl = (char*)Blds[j];
            int bkob = g * 64 + chunkb;
#pragma unroll
            for (int r = 0; r < RB; ++r)
                load16(bqb + (size_t)(r * 64 + bco) * K * 2 + bkob, Bl + r * 4096 + tid * 16);
        }
        __syncthreads();
#pragma unroll
        for (int j = 0; j < G; ++j) {
            const char* Al = (const char*)Alds[j];
            const char* Bl = (const char*)Blds[j];
            bf16x8 af[4], bf[NT];
#pragma unroll
            for (int mt = 0; mt < 4; ++mt)
                af[mt] = *(const bf16x8*)(Al + (wm * 4 + mt) * 1024 + fr16);
#pragma unroll
            for (int nt = 0; nt < NT; ++nt)
                bf[nt] = *(const bf16x8*)(Bl + (wn * NT + nt) * 1024 + fr16);
#pragma unroll
            for (int mt = 0; mt < 4; ++mt)
#pragma unroll
                for (int nt = 0; nt < NT; ++nt)
                    acc[mt][nt] = __builtin_amdgcn_mfma_f32_16x16x32_bf16(af[mt], bf[nt], acc[mt][nt], 0, 0, 0);
        }
        __syncthreads();
    }

    const int fr = lane & 15, quad = lane >> 4;
    if (POOL) {
#pragma unroll
        for (int mt = 0; mt < 4; ++mt) {
            int pl = wm * 16 + mt * 4 + quad;
            int ob = rowO[pl];
#pragma unroll
            for (int nt = 0; nt < NT; ++nt) {
                int col = wn * (NT * 16) + nt * 16 + fr;
                float sc = scl[col], sh = sft[col];
                f32x4 a = acc[mt][nt];
                float v0 = a[0] * sc + sh, v1 = a[1] * sc + sh;
                float v2 = a[2] * sc + sh, v3 = a[3] * sc + sh;
                float mx = fmaxf(fmaxf(v0, v1), fmaxf(v2, v3));
                out[(size_t)ob + col] = f2b(fmaxf(mx, 0.f));
            }
        }
    } else {
#pragma unroll
        for (int mt = 0; mt < 4; ++mt) {
            int rb = wm * 64 + mt * 16 + quad * 4;
            int o0 = rowO[rb], o1 = rowO[rb + 1], o2 = rowO[rb + 2], o3 = rowO[rb + 3];
#pragma unroll
            for (int nt = 0; nt < NT; ++nt) {
                int col = wn * (NT * 16) + nt * 16 + fr;
                float sc = scl[col], sh = sft[col];
                f32x4 a = acc[mt][nt];
                out[(size_t)o0 + col] = f2b(fmaxf(a[0] * sc + sh, 0.f));
                out[(size_t)o1 + col] = f2b(fmaxf(a[1] * sc + sh, 0.f));
                out[(size_t)o2 + col] = f2b(fmaxf(a[2] * sc + sh, 0.f));
                out[(size_t)o3 + col] = f2b(fmaxf(a[3] * sc + sh, 0.f));
            }
        }
    }
}

// ---------------- conv34 v2: per-image fused conv3+conv4+pool ----------------
// Row-major M (256 rows incl. junk borders): tap reads are r = m + const ->
// r&15 distinct per quad-group -> swizzle pos = c^(r&N) conflict-free.
// 4 waves row-split (no A duplication), nt=8 (all 128 cols; B global/L1-hot).
// Pool runs post-conv4 through LDS (reuses X3's 64KB). 4 barriers total.
__global__ __launch_bounds__(256, 2)
void conv34(const u16* __restrict__ act2p, const u16* __restrict__ b3p, const u16* __restrict__ b4p,
            const float* __restrict__ b3, const float* __restrict__ g3, const float* __restrict__ be3,
            const float* __restrict__ m3, const float* __restrict__ v3,
            const float* __restrict__ b4, const float* __restrict__ g4, const float* __restrict__ be4,
            const float* __restrict__ m4, const float* __restrict__ v4,
            u16* __restrict__ out) {
    __shared__ __align__(16) u16 Xs[32768];   // 64KB: X2 [0,32K) then X3/X4 [0,64K)

    const int tid = threadIdx.x;
    const int n = blockIdx.x;
    const int w = tid >> 6, lane = tid & 63;
    const int fr = lane & 15, quad = lane >> 4;
    char* X = (char*)Xs;

    // phase A: stage X2 (256 rows x 128B, chunk c at pos c^(r&7))
    {
        const uint4* src = (const uint4*)(act2p + (size_t)n * 16384);
#pragma unroll
        for (int it = 0; it < 8; ++it) {
            int i = it * 256 + tid;
            int r = i >> 3, c = i & 7;
            uint4 v = src[i];
            *(uint4*)(X + r * 128 + ((c ^ (r & 7)) << 4)) = v;
        }
    }
    __syncthreads();

    const int mb = w * 64 + fr;   // wave's A-row base (+ mt*16)
    f32x4 acc[4][8];
#pragma unroll
    for (int a = 0; a < 4; ++a)
#pragma unroll
        for (int b = 0; b < 8; ++b) acc[a][b] = (f32x4){0.f, 0.f, 0.f, 0.f};

    // phase B: conv3, K=576 (9 taps x 2 halves), barrier-free
    const char* B3 = (const char*)b3p;
#pragma unroll
    for (int tap = 0; tap < 9; ++tap) {
        const int off = (tap / 3 - 1) * 16 + (tap % 3 - 1);
        int r[4];
#pragma unroll
        for (int mt = 0; mt < 4; ++mt) r[mt] = (mb + mt * 16 + off) & 255;
#pragma unroll
        for (int h = 0; h < 2; ++h) {
            const int s = tap * 2 + h;
            bf16x8 af[4], bf[8];
#pragma unroll
            for (int mt = 0; mt < 4; ++mt) {
                int pos = (h * 4 + quad) ^ (r[mt] & 7);
                af[mt] = *(const bf16x8*)(X + r[mt] * 128 + pos * 16);
            }
#pragma unroll
            for (int nt = 0; nt < 8; ++nt)
                bf[nt] = *(const bf16x8*)(B3 + (size_t)((s * 8 + nt) * 64 + lane) * 16);
#pragma unroll
            for (int mt = 0; mt < 4; ++mt)
#pragma unroll
                for (int nt = 0; nt < 8; ++nt)
                    acc[mt][nt] = __builtin_amdgcn_mfma_f32_16x16x32_bf16(af[mt], bf[nt], acc[mt][nt], 0, 0, 0);
        }
    }
    __syncthreads();   // all X2 reads done; X3 (64KB) may overwrite

    // phase C: build X3 (256 rows x 256B, chunk c at pos c^(r&15)); borders zero
    {
        float scl3[8], sft3[8];
#pragma unroll
        for (int nt = 0; nt < 8; ++nt) {
            int c = nt * 16 + fr;
            float s = g3[c] * rsqrtf(v3[c] + BN_EPS);
            scl3[nt] = s;
            sft3[nt] = (b3[c] - m3[c]) * s + be3[c];
        }
        for (int t = tid; t < 960; t += 256) {
            int ch = t & 15, b = t >> 4;
            int m = (b < 16) ? b : (b < 32) ? 224 + b : (b < 46) ? (b - 31) * 16 : (b - 45) * 16 + 15;
            *(uint4*)(X + m * 256 + ((ch ^ (m & 15)) << 4)) = make_uint4(0, 0, 0, 0);
        }
#pragma unroll
        for (int mt = 0; mt < 4; ++mt) {
            int y = w * 4 + mt;
            if (y >= 1 && y <= 14) {
#pragma unroll
                for (int j = 0; j < 4; ++j) {
                    int x = quad * 4 + j;
                    if (x >= 1 && x <= 14) {
                        int m = y * 16 + x;
#pragma unroll
                        for (int nt = 0; nt < 8; ++nt) {
                            int col = nt * 16 + fr;
                            float v = fmaxf(acc[mt][nt][j] * scl3[nt] + sft3[nt], 0.f);
                            *(u16*)(X + m * 256 + (((col >> 3) ^ (m & 15)) << 4) + (col & 7) * 2) = f2b(v);
                        }
                    }
                }
            }
        }
    }
    __syncthreads();

    // phase D: conv4, K=1152 (9 taps x 4 quarters), barrier-free
#pragma unroll
    for (int a = 0; a < 4; ++a)
#pragma unroll
        for (int b = 0; b < 8; ++b) acc[a][b] = (f32x4){0.f, 0.f, 0.f, 0.f};
    const char* B4 = (const char*)b4p;
#pragma unroll
    for (int tap = 0; tap < 9; ++tap) {
        const int off = (tap / 3 - 1) * 16 + (tap % 3 - 1);
        int r[4];
#pragma unroll
        for (int mt = 0; mt < 4; ++mt) r[mt] = (mb + mt * 16 + off) & 255;
#pragma unroll
        for (int qr = 0; qr < 4; ++qr) {
            const int s = tap * 4 + qr;
            bf16x8 af[4], bf[8];
#pragma unroll
            for (int mt = 0; mt < 4; ++mt) {
                int pos = (qr * 4 + quad) ^ (r[mt] & 15);
                af[mt] = *(const bf16x8*)(X + r[mt] * 256 + pos * 16);
            }
#pragma unroll
            for (int nt = 0; nt < 8; ++nt)
                bf[nt] = *(const bf16x8*)(B4 + (size_t)((s * 8 + nt) * 64 + lane) * 16);
#pragma unroll
            for (int mt = 0; mt < 4; ++mt)
#pragma unroll
                for (int nt = 0; nt < 8; ++nt)
                    acc[mt][nt] = __builtin_amdgcn_mfma_f32_16x16x32_bf16(af[mt], bf[nt], acc[mt][nt], 0, 0, 0);
        }
    }
    __syncthreads();   // X3 reads done; reuse as X4

    // phase E: write post-BN-ReLU conv4 (all rows; junk never read by pool)
    {
        float scl4[8], sft4[8];
#pragma unroll
        for (int nt = 0; nt < 8; ++nt) {
            int c = nt * 16 + fr;
            float s = g4[c] * rsqrtf(v4[c] + BN_EPS);
            scl4[nt] = s;
            sft4[nt] = (b4[c] - m4[c]) * s + be4[c];
        }
#pragma unroll
        for (int mt = 0; mt < 4; ++mt) {
#pragma unroll
            for (int j = 0; j < 4; ++j) {
                int m = w * 64 + mt * 16 + quad * 4 + j;
#pragma unroll
                for (int nt = 0; nt < 8; ++nt) {
                    int col = nt * 16 + fr;
                    float v = fmaxf(acc[mt][nt][j] * scl4[nt] + sft4[nt], 0.f);
                    *(u16*)(X + m * 256 + (((col >> 3) ^ (m & 15)) << 4) + (col & 7) * 2) = f2b(v);
                }
            }
        }
    }
    __syncthreads();

    // pool phase: 49 px x 16 chunks; bf16 >= 0 so u16 compare == float compare
    for (int t = tid; t < 784; t += 256) {
        int ch = t & 15, p = t >> 4;
        int oy = p / 7, ox = p % 7;
        int r00 = (2 * oy + 1) * 16 + (2 * ox + 1);
        int r01 = r00 + 1, r10 = r00 + 16, r11 = r00 + 17;
        uint4 A0 = *(const uint4*)(X + r00 * 256 + ((ch ^ (r00 & 15)) << 4));
        uint4 A1 = *(const uint4*)(X + r01 * 256 + ((ch ^ (r01 & 15)) << 4));
        uint4 A2 = *(const uint4*)(X + r10 * 256 + ((ch ^ (r10 & 15)) << 4));
        uint4 A3 = *(const uint4*)(X + r11 * 256 + ((ch ^ (r11 & 15)) << 4));
        const u16* pa = (const u16*)&A0;
        const u16* pb = (const u16*)&A1;
        const u16* pc = (const u16*)&A2;
        const u16* pd = (const u16*)&A3;
        u16 o[8];
#pragma unroll
        for (int e = 0; e < 8; ++e)
            o[e] = (u16)max(max((int)pa[e], (int)pb[e]), max((int)pc[e], (int)pd[e]));
        *(uint4*)(out + ((size_t)n * 49 + p) * 128 + ch * 8) = *(const uint4*)o;
    }
}

// ---------------- fc1: split-K MFMA GEMM (LDS dbuf), atomicAdd f32 into f1 ----------------
__global__ __launch_bounds__(256)
void fc1gemm(const u16* __restrict__ A, const u16* __restrict__ Bq, float* __restrict__ out) {
    constexpr int K = 6272, KC = 896, S = KC / 64;
    __shared__ __align__(16) u16 Alds[2][128 * 32];
    __shared__ __align__(16) u16 Blds[2][128 * 32];
    const int tid = threadIdx.x;
    const int m0 = blockIdx.x * 128;
    const int n0 = blockIdx.y * 128;
    const int k0 = blockIdx.z * KC;
    const int chunkb = ((tid >> 4) & 3) * 16;
    const int rr = (tid >> 6) * 16 + (tid & 15);
    const char* Ag = (const char*)A;
    const char* Bg = (const char*)Bq;
    const int wave = tid >> 6, lane = tid & 63;
    const int wm = wave & 1, wn = wave >> 1;
    const int fr16 = lane * 16;
    f32x4 acc[4][4] = {};

    for (int s = 0; s < S; ++s) {
#pragma unroll
        for (int j = 0; j < 2; ++j) {
            int kb = (k0 + s * 64 + j * 32) * 2 + chunkb;
            char* Al = (char*)Alds[j];
            char* Bl = (char*)Blds[j];
#pragma unroll
            for (int r = 0; r < 2; ++r) {
                load16(Ag + (size_t)(m0 + r * 64 + rr) * K * 2 + kb, Al + r * 4096 + tid * 16);
                load16(Bg + (size_t)(n0 + r * 64 + rr) * K * 2 + kb, Bl + r * 4096 + tid * 16);
            }
        }
        __syncthreads();
#pragma unroll
        for (int j = 0; j < 2; ++j) {
            const char* Al = (const char*)Alds[j];
            const char* Bl = (const char*)Blds[j];
            bf16x8 af[4], bf[4];
#pragma unroll
            for (int mt = 0; mt < 4; ++mt)
                af[mt] = *(const bf16x8*)(Al + (wm * 4 + mt) * 1024 + fr16);
#pragma unroll
            for (int nt = 0; nt < 4; ++nt)
                bf[nt] = *(const bf16x8*)(Bl + (wn * 4 + nt) * 1024 + fr16);
#pragma unroll
            for (int mt = 0; mt < 4; ++mt)
#pragma unroll
                for (int nt = 0; nt < 4; ++nt)
                    acc[mt][nt] = __builtin_amdgcn_mfma_f32_16x16x32_bf16(af[mt], bf[nt], acc[mt][nt], 0, 0, 0);
        }
        __syncthreads();
    }
    const int fr = lane & 15, quad = lane >> 4;
#pragma unroll
    for (int mt = 0; mt < 4; ++mt) {
        int row = m0 + wm * 64 + mt * 16 + quad * 4;
#pragma unroll
        for (int nt = 0; nt < 4; ++nt) {
            int col = n0 + wn * 64 + nt * 16 + fr;
            f32x4 a = acc[mt][nt];
            atomicAdd(&out[(size_t)(row + 0) * 256 + col], a[0]);
            atomicAdd(&out[(size_t)(row + 1) * 256 + col], a[1]);
            atomicAdd(&out[(size_t)(row + 2) * 256 + col], a[2]);
            atomicAdd(&out[(size_t)(row + 3) * 256 + col], a[3]);
        }
    }
}

// ---------------- fc2 fp32 GEMM; applies fc1's BN+ReLU to A on load ----------------
__global__ __launch_bounds__(256)
void fc2_kernel(const float* __restrict__ A, const float* __restrict__ Bw,
                const float* __restrict__ bA, const float* __restrict__ gA,
                const float* __restrict__ beA, const float* __restrict__ mA,
                const float* __restrict__ vA,
                const float* __restrict__ bias, const float* __restrict__ gam,
                const float* __restrict__ bet, const float* __restrict__ mu,
                const float* __restrict__ var, float* __restrict__ out) {
    constexpr int Nn = 128, K = 256;
    __shared__ __align__(16) float As[16][68];
    __shared__ __align__(16) float Bs[16][68];
    __shared__ float sclA[256], sftA[256];
    const int tid = threadIdx.x;
    const int n0 = blockIdx.x * 64, m0 = blockIdx.y * 64;
    if (tid < 256) {
        float s = gA[tid] * rsqrtf(vA[tid] + BN_EPS);
        sclA[tid] = s;
        sftA[tid] = (bA[tid] - mA[tid]) * s + beA[tid];
    }
    const int tm = tid >> 4, tn = tid & 15;
    const int lr = tid >> 2, lk = (tid & 3) * 4;
    float acc[4][4] = {};
    __syncthreads();
    for (int k0 = 0; k0 < K; k0 += 16) {
        float4 av = *(const float4*)&A[(size_t)(m0 + lr) * K + k0 + lk];
        float4 bv = *(const float4*)&Bw[(size_t)(n0 + lr) * K + k0 + lk];
        As[lk + 0][lr] = fmaxf(av.x * sclA[k0 + lk + 0] + sftA[k0 + lk + 0], 0.f);
        As[lk + 1][lr] = fmaxf(av.y * sclA[k0 + lk + 1] + sftA[k0 + lk + 1], 0.f);
        As[lk + 2][lr] = fmaxf(av.z * sclA[k0 + lk + 2] + sftA[k0 + lk + 2], 0.f);
        As[lk + 3][lr] = fmaxf(av.w * sclA[k0 + lk + 3] + sftA[k0 + lk + 3], 0.f);
        Bs[lk + 0][lr] = bv.x; Bs[lk + 1][lr] = bv.y; Bs[lk + 2][lr] = bv.z; Bs[lk + 3][lr] = bv.w;
        __syncthreads();
#pragma unroll
        for (int k = 0; k < 16; ++k) {
            float4 a = *(const float4*)&As[k][tm * 4];
            float4 b = *(const float4*)&Bs[k][tn * 4];
            acc[0][0] += a.x * b.x; acc[0][1] += a.x * b.y; acc[0][2] += a.x * b.z; acc[0][3] += a.x * b.w;
            acc[1][0] += a.y * b.x; acc[1][1] += a.y * b.y; acc[1][2] += a.y * b.z; acc[1][3] += a.y * b.w;
            acc[2][0] += a.z * b.x; acc[2][1] += a.z * b.y; acc[2][2] += a.z * b.z; acc[2][3] += a.z * b.w;
            acc[3][0] += a.w * b.x; acc[3][1] += a.w * b.y; acc[3][2] += a.w * b.z; acc[3][3] += a.w * b.w;
        }
        __syncthreads();
    }
#pragma unroll
    for (int i = 0; i < 4; ++i) {
        int row = m0 + tm * 4 + i;
#pragma unroll
        for (int j = 0; j < 4; ++j) {
            int col = n0 + tn * 4 + j;
            float sc = gam[col] * rsqrtf(var[col] + BN_EPS);
            float v = (acc[i][j] + bias[col] - mu[col]) * sc + bet[col];
            out[(size_t)row * Nn + col] = fmaxf(v, 0.f);
        }
    }
}

__global__ __launch_bounds__(256)
void fc3_kernel(const float* __restrict__ A, const float* __restrict__ Bw,
                const float* __restrict__ bias, float* __restrict__ out) {
    int i = blockIdx.x * blockDim.x + threadIdx.x;
    if (i >= 1024 * 10) return;
    int n = i / 10, j = i % 10;
    const float4* a = (const float4*)&A[(size_t)n * 128];
    const float4* b = (const float4*)&Bw[(size_t)j * 128];
    float s = 0.f;
#pragma unroll
    for (int k = 0; k < 32; ++k) {
        float4 x = a[k], y = b[k];
        s += x.x * y.x + x.y * y.y + x.z * y.z + x.w * y.w;
    }
    out[i] = s + bias[j];
}

extern "C" void kernel_launch(void* const* d_in, const int* in_sizes, int n_in,
                              void* d_out, int out_size, void* d_ws, size_t ws_size,
                              hipStream_t stream) {
    (void)in_sizes; (void)n_in; (void)out_size; (void)ws_size;
    const float* x   = (const float*)d_in[0];
    const float* w1  = (const float*)d_in[1];
    const float* w2  = (const float*)d_in[2];
    const float* w3  = (const float*)d_in[3];
    const float* w4  = (const float*)d_in[4];
    const float* wf1 = (const float*)d_in[5];
    const float* wf2 = (const float*)d_in[6];
    const float* wf3 = (const float*)d_in[7];
    auto P = [&](int i) { return (const float*)d_in[i]; };
    char* wsb = (char*)d_ws;
    float* sums = (float*)(wsb + O_SUMS);
    float* w1r  = (float*)(wsb + O_W1R);
    float* wf2q = (float*)(wsb + O_WF2Q);
    float* wf3q = (float*)(wsb + O_WF3Q);
    u16* bq2   = (u16*)(wsb + O_BQ2);
    u16* bq3p  = (u16*)(wsb + O_BQ3);
    u16* bq4p  = (u16*)(wsb + O_BQ4);
    u16* bqf1  = (u16*)(wsb + O_BQF1);
    float* f1  = (float*)(wsb + O_F1);
    float* f2  = (float*)(wsb + O_F2);
    u16* act1  = (u16*)(wsb + O_ACT1);
    u16* act2p = (u16*)(wsb + O_ACT2);
    u16* act4p = (u16*)(wsb + O_ACT4);

    // ternarization: 3 launches
    zero_sums<<<1, 64, 0, stream>>>(sums);
    absmean_all<<<226, 256, 0, stream>>>(w1, w2, w3, w4, wf1, wf2, wf3, sums);
    tern_all<<<634, 256, 0, stream>>>(w1, w2, w3, w4, wf1, wf2, wf3, sums,
                                      w1r, bq2, bq3p, bq4p, bqf1, wf2q, wf3q);

    // border zeros + f1 zero (independent)
    border_zero<32, 30, 28><<<(1024 * 116 * 4 + 255) / 256, 256, 0, stream>>>(act1);
    border_zero<64, 16, 14><<<(1024 * 60 * 8 + 255) / 256, 256, 0, stream>>>(act2p);
    zero_f1<<<256, 256, 0, stream>>>(f1);

    // conv1 -> act1 (pad30 interior)
    conv1_direct<<<1024, 256, 0, stream>>>(x, w1r, P(8), P(9), P(10), P(11), P(12), act1);
    // conv2 + fused pool -> act2p (pad16 C=64 interior)
    convgemm<32, 64, 28, 30, 1, true, true><<<6272, 256, 0, stream>>>(
        act1, bq2, P(13), P(14), P(15), P(16), P(17), act2p);
    // fused conv3+conv4+pool -> act4p [1024*49][128]
    conv34<<<1024, 256, 0, stream>>>(
        act2p, bq3p, bq4p,
        P(18), P(19), P(20), P(21), P(22),
        P(23), P(24), P(25), P(26), P(27), act4p);
    // fc1 split-K (7 chunks of 896) -> atomic f32 into f1
    fc1gemm<<<dim3(8, 2, 7), 256, 0, stream>>>(act4p, bqf1, f1);
    // fc2 (applies fc1 BN+ReLU on A-load) -> f2
    fc2_kernel<<<dim3(2, 16), 256, 0, stream>>>(
        f1, wf2q, P(28), P(29), P(30), P(31), P(32),
        P(33), P(34), P(35), P(36), P(37), f2);
    // fc3 -> logits
    fc3_kernel<<<40, 256, 0, stream>>>(f2, wf3q, P(38), (float*)d_out);
}

// Round 9
// 443.254 us; speedup vs baseline: 1.6123x; 1.6123x over previous
//
#include <hip/hip_runtime.h>
#include <hip/hip_bf16.h>

#define BN_EPS 1e-5f

typedef __attribute__((ext_vector_type(8))) short bf16x8;
typedef __attribute__((ext_vector_type(4))) float f32x4;
typedef unsigned short u16;
typedef unsigned int u32;

__device__ __forceinline__ void load16(const void* g, void* l) {
    __builtin_amdgcn_global_load_lds((const __attribute__((address_space(1))) void*)g,
                                     (__attribute__((address_space(3))) void*)l, 16, 0, 0);
}
__device__ __forceinline__ u16 f2b(float v) {
    __hip_bfloat16 h = __float2bfloat16(v);
    return *reinterpret_cast<u16*>(&h);
}
__device__ __forceinline__ float ternq(float x, float d) {
    return (fabsf(x) > d) ? (x > 0.f ? 1.f : -1.f) : 0.f;
}

// ---------------- ws layout (BYTE offsets) ----------------
constexpr size_t ALGN(size_t x) { return (x + 255) & ~(size_t)255; }
constexpr size_t O_SUMS = 0;                                   // 8 f32
constexpr size_t O_W1R  = 256;                                 // 288 f32
constexpr size_t O_WF2Q = ALGN(O_W1R + 288 * 4);               // 32768 f32
constexpr size_t O_WF3Q = ALGN(O_WF2Q + 32768 * 4);            // 1280 f32
constexpr size_t O_BQ2  = ALGN(O_WF3Q + 1280 * 4);             // [64][288] bf16 (frag layout)
constexpr size_t O_BQ3  = ALGN(O_BQ2 + 64 * 288 * 2);          // B3' primed [18][8][64][8] bf16
constexpr size_t O_BQ4  = ALGN(O_BQ3 + 128 * 576 * 2);         // B4' primed [36][8][64][8] bf16
constexpr size_t O_BQF1 = ALGN(O_BQ4 + 128 * 1152 * 2);        // [256][6272] bf16
constexpr size_t O_F1   = ALGN(O_BQF1 + (size_t)256 * 6272 * 2);  // [1024][256] f32
constexpr size_t O_F2   = ALGN(O_F1 + 1024 * 256 * 4);         // [1024][128] f32
constexpr size_t O_ACT1 = ALGN(O_F2 + 1024 * 128 * 4);         // pad30 C=32 bf16
constexpr size_t O_ACT2 = ALGN(O_ACT1 + (size_t)1024 * 900 * 32 * 2);  // pad16 C=64
constexpr size_t O_ACT3 = ALGN(O_ACT2 + (size_t)1024 * 256 * 64 * 2);  // (unused)
constexpr size_t O_ACT4 = ALGN(O_ACT3 + (size_t)1024 * 256 * 128 * 2); // [1024*49][128]

// ---------------- ternarization (merged) ----------------
__global__ void zero_sums(float* s) { if (threadIdx.x < 8) s[threadIdx.x] = 0.f; }

__device__ void absmean_seg(const float* __restrict__ w, int n4, float* __restrict__ sum,
                            int b0, int nb) {
    __shared__ float sm[256];
    float s = 0.f;
    for (int i = b0 * 256 + threadIdx.x; i < n4; i += nb * 256) {
        float4 v = ((const float4*)w)[i];
        s += fabsf(v.x) + fabsf(v.y) + fabsf(v.z) + fabsf(v.w);
    }
    sm[threadIdx.x] = s;
    __syncthreads();
    for (int o = 128; o > 0; o >>= 1) {
        if (threadIdx.x < o) sm[threadIdx.x] += sm[threadIdx.x + o];
        __syncthreads();
    }
    if (threadIdx.x == 0) atomicAdd(sum, sm[0]);
}

__global__ void absmean_all(const float* w1, const float* w2, const float* w3, const float* w4,
                            const float* wf1, const float* wf2, const float* wf3, float* sums) {
    int b = blockIdx.x;
    if (b < 160)      absmean_seg(wf1, 401408, sums + 4, b, 160);
    else if (b < 192) absmean_seg(w4, 36864, sums + 3, b - 160, 32);
    else if (b < 208) absmean_seg(w3, 18432, sums + 2, b - 192, 16);
    else if (b < 216) absmean_seg(w2, 4608, sums + 1, b - 208, 8);
    else if (b < 224) absmean_seg(wf2, 8192, sums + 5, b - 216, 8);
    else if (b < 225) absmean_seg(w1, 72, sums + 0, 0, 1);
    else              absmean_seg(wf3, 320, sums + 6, 0, 1);
}

// conv2 weights: src [co][ci][9] -> frag layout [co][tap*CIN+ci]
__device__ void tern_conv_seg(const float* __restrict__ w, float d, u16* __restrict__ bq,
                              int COUT, int CIN, int b0, int nb) {
    int N = COUT * CIN * 9;
    for (int i = b0 * 256 + threadIdx.x; i < N; i += nb * 256) {
        float q = ternq(w[i], d);
        int co = i / (CIN * 9), r = i % (CIN * 9);
        int ci = r / 9, tap = r % 9;
        bq[(size_t)co * CIN * 9 + tap * CIN + ci] = f2b(q);
    }
}
// conv3/4 weights -> primed coalesced layout [s][nt][lane][8] (COUT=128)
__device__ void tern_conv_prime_seg(const float* __restrict__ w, float d, u16* __restrict__ bqp,
                                    int CIN, int b0, int nb) {
    int N = 128 * CIN * 9;
    for (int i = b0 * 256 + threadIdx.x; i < N; i += nb * 256) {
        float q = ternq(w[i], d);
        int co = i / (CIN * 9), r = i % (CIN * 9);
        int ci = r / 9, tap = r % 9;
        int k = tap * CIN + ci;
        int s = k >> 5, qd = (k & 31) >> 3, e = k & 7;
        int lane = qd * 16 + (co & 15), nt = co >> 4;
        bqp[((size_t)(s * 8 + nt) * 64 + lane) * 8 + e] = f2b(q);
    }
}
__device__ void tern_f32_seg(const float* __restrict__ w, float d, float* __restrict__ wq,
                             int N, int b0, int nb) {
    for (int i = b0 * 256 + threadIdx.x; i < N; i += nb * 256) wq[i] = ternq(w[i], d);
}

__global__ void tern_all(const float* w1, const float* w2, const float* w3, const float* w4,
                         const float* wf1, const float* wf2, const float* wf3,
                         const float* __restrict__ sums,
                         float* w1r, u16* bq2, u16* bq3p, u16* bq4p, u16* bqf1,
                         float* wf2q, float* wf3q) {
    int b = blockIdx.x;
    if (b < 1) {
        tern_f32_seg(w1, 0.7f * sums[0] / 288.f, w1r, 288, 0, 1);
    } else if (b < 9) {
        tern_conv_seg(w2, 0.7f * sums[1] / 18432.f, bq2, 64, 32, b - 1, 8);
    } else if (b < 41) {
        tern_conv_prime_seg(w3, 0.7f * sums[2] / 73728.f, bq3p, 64, b - 9, 32);
    } else if (b < 105) {
        tern_conv_prime_seg(w4, 0.7f * sums[3] / 147456.f, bq4p, 128, b - 41, 64);
    } else if (b < 617) {
        // wf1 [256][6272], k=c*49+s -> bf16 [256][s*128+c]
        float d = 0.7f * sums[4] / 1605632.f;
        for (int i = (b - 105) * 256 + threadIdx.x; i < 1605632; i += 512 * 256) {
            float q = ternq(wf1[i], d);
            int j = i / 6272, k = i % 6272;
            int c = k / 49, s = k % 49;
            bqf1[(size_t)j * 6272 + s * 128 + c] = f2b(q);
        }
    } else if (b < 633) {
        tern_f32_seg(wf2, 0.7f * sums[5] / 32768.f, wf2q, 32768, b - 617, 16);
    } else {
        tern_f32_seg(wf3, 0.7f * sums[6] / 1280.f, wf3q, 1280, 0, 1);
    }
}

__global__ void zero_f1(float* f1) {
    ((float4*)f1)[blockIdx.x * 256 + threadIdx.x] = make_float4(0.f, 0.f, 0.f, 0.f);
}

// ---------------- conv1 direct (Cin=1) -> pad30 NHWC bf16 ----------------
__global__ __launch_bounds__(256)
void conv1_direct(const float* __restrict__ x, const float* __restrict__ w1r,
                  const float* __restrict__ bias, const float* __restrict__ gam,
                  const float* __restrict__ bet, const float* __restrict__ mu,
                  const float* __restrict__ var, u16* __restrict__ out) {
    __shared__ float xs[784];
    __shared__ float wsh[288];
    __shared__ float scl[32], sft[32];
    const int n = blockIdx.x, tid = threadIdx.x;
    for (int i = tid; i < 784; i += 256) xs[i] = x[(size_t)n * 784 + i];
    for (int i = tid; i < 288; i += 256) wsh[i] = w1r[i];
    if (tid < 32) {
        float s = gam[tid] * rsqrtf(var[tid] + BN_EPS);
        scl[tid] = s;
        sft[tid] = (bias[tid] - mu[tid]) * s + bet[tid];
    }
    __syncthreads();
    for (int p = tid; p < 784; p += 256) {
        int y = p / 28, xx = p % 28;
        float patch[9];
#pragma unroll
        for (int dy = 0; dy < 3; ++dy)
#pragma unroll
            for (int dx = 0; dx < 3; ++dx) {
                int gy = y + dy - 1, gx = xx + dx - 1;
                patch[dy * 3 + dx] = (gy >= 0 && gy < 28 && gx >= 0 && gx < 28) ? xs[gy * 28 + gx] : 0.f;
            }
        u32 pk[16];
#pragma unroll
        for (int co = 0; co < 32; co += 2) {
            float s0 = 0.f, s1 = 0.f;
#pragma unroll
            for (int t = 0; t < 9; ++t) {
                s0 += wsh[co * 9 + t] * patch[t];
                s1 += wsh[(co + 1) * 9 + t] * patch[t];
            }
            float v0 = fmaxf(s0 * scl[co] + sft[co], 0.f);
            float v1 = fmaxf(s1 * scl[co + 1] + sft[co + 1], 0.f);
            pk[co >> 1] = ((u32)f2b(v1) << 16) | (u32)f2b(v0);
        }
        size_t base = ((size_t)(n * 30 + y + 1) * 30 + (xx + 1)) * 32;
#pragma unroll
        for (int q = 0; q < 4; ++q) ((uint4*)(out + base))[q] = ((uint4*)pk)[q];
    }
}

// ---------------- border zero for padded NHWC buffers ----------------
template<int C, int HP, int HV>
__global__ void border_zero(u16* __restrict__ buf) {
    constexpr int NB = 2 * HP + 2 * HV;
    constexpr int CG = C / 8;
    int i = blockIdx.x * blockDim.x + threadIdx.x;
    if (i >= 1024 * NB * CG) return;
    int cg = i % CG, r = i / CG;
    int b = r % NB, n = r / NB;
    int py, px;
    if (b < HP)               { py = 0;                  px = b; }
    else if (b < 2 * HP)      { py = HP - 1;             px = b - HP; }
    else if (b < 2 * HP + HV) { py = b - 2 * HP + 1;     px = 0; }
    else                      { py = b - 2 * HP - HV + 1; px = HP - 1; }
    size_t off = ((size_t)(n * HP + py) * HP + px) * C + cg * 8;
    *(uint4*)(buf + off) = make_uint4(0, 0, 0, 0);
}

// ---------------- conv2: R3-style implicit GEMM, frag-major LDS, fused pool ----------------
template<int CIN, int BN, int HV, int HP, int G, bool POOL, bool PADOUT>
__global__ __launch_bounds__(256)
void convgemm(const u16* __restrict__ act, const u16* __restrict__ bq,
              const float* __restrict__ bias, const float* __restrict__ gam,
              const float* __restrict__ bet, const float* __restrict__ mu,
              const float* __restrict__ var, u16* __restrict__ out) {
    constexpr int BM = 128;
    constexpr int K = 9 * CIN;
    constexpr int S = K / (32 * G);
    constexpr int TPC = CIN / 32;
    constexpr int NT = BN / 32;
    constexpr int RB = BN / 64;
    constexpr int HO = HV / 2;
    constexpr int PP = POOL ? HO * HO : HV * HV;

    __shared__ __align__(16) u16 Alds[G][BM * 32];
    __shared__ __align__(16) u16 Blds[G][BN * 32];
    __shared__ int rowA[BM];
    __shared__ int rowO[BM];
    __shared__ float scl[BN], sft[BN];

    const int tid = threadIdx.x;
    const int m0 = blockIdx.x * BM;

    for (int t = tid; t < BM; t += 256) {
        int base;
        if (POOL) {
            int p = (m0 >> 2) + (t >> 2), q = t & 3;
            int n = p / PP, rr = p % PP;
            int oy = rr / HO, ox = rr % HO;
            int y = oy * 2 + (q >> 1), x = ox * 2 + (q & 1);
            base = ((n * HP + y) * HP + x) * CIN;
        } else {
            int m = m0 + t;
            int n = m / PP, rr = m % PP;
            int y = rr / HV, x = rr % HV;
            base = ((n * HP + y) * HP + x) * CIN;
        }
        rowA[t] = base;
    }
    if (POOL) {
        if (tid < 32) {
            int p = (m0 >> 2) + tid;
            int n = p / PP, rr = p % PP;
            int oy = rr / HO, ox = rr % HO;
            rowO[tid] = PADOUT ? ((n * 16 + oy + 1) * 16 + ox + 1) * BN : p * BN;
        }
    } else {
        for (int t = tid; t < BM; t += 256) {
            int m = m0 + t;
            int n = m / PP, rr = m % PP;
            int y = rr / HV, x = rr % HV;
            rowO[t] = PADOUT ? ((n * 16 + y + 1) * 16 + x + 1) * BN : m * BN;
        }
    }
    if (tid < BN) {
        float s = gam[tid] * rsqrtf(var[tid] + BN_EPS);
        scl[tid] = s;
        sft[tid] = (bias[tid] - mu[tid]) * s + bet[tid];
    }
    __syncthreads();

    int arow[2];
    arow[0] = rowA[(tid >> 6) * 16 + (tid & 15)];
    arow[1] = rowA[64 + (tid >> 6) * 16 + (tid & 15)];
    const int chunkb = ((tid >> 4) & 3) * 16;
    const int bco = (tid >> 6) * 16 + (tid & 15);
    const char* actb = (const char*)act;
    const char* bqb  = (const char*)bq;

    const int wave = tid >> 6, lane = tid & 63;
    const int wm = wave & 1, wn = wave >> 1;
    const int fr16 = lane * 16;

    f32x4 acc[4][NT] = {};

    for (int s = 0; s < S; ++s) {
#pragma unroll
        for (int j = 0; j < G; ++j) {
            int g = s * G + j;
            int tap = g / TPC, cio = (g % TPC) * 32;
            int dy = tap / 3, dx = tap % 3;
            int toffb = ((dy * HP + dx) * CIN + cio) * 2;
            char* Al = (char*)Alds[j];
#pragma unroll
            for (int r = 0; r < 2; ++r)
                load16(actb + (size_t)arow[r] * 2 + toffb + chunkb, Al + r * 4096 + tid * 16);
            char* Bl = (char*)Blds[j];
            int bkob = g * 64 + chunkb;
#pragma unroll
            for (int r = 0; r < RB; ++r)
                load16(bqb + (size_t)(r * 64 + bco) * K * 2 + bkob, Bl + r * 4096 + tid * 16);
        }
        __syncthreads();
#pragma unroll
        for (int j = 0; j < G; ++j) {
            const char* Al = (const char*)Alds[j];
            const char* Bl = (const char*)Blds[j];
            bf16x8 af[4], bf[NT];
#pragma unroll
            for (int mt = 0; mt < 4; ++mt)
                af[mt] = *(const bf16x8*)(Al + (wm * 4 + mt) * 1024 + fr16);
#pragma unroll
            for (int nt = 0; nt < NT; ++nt)
                bf[nt] = *(const bf16x8*)(Bl + (wn * NT + nt) * 1024 + fr16);
#pragma unroll
            for (int mt = 0; mt < 4; ++mt)
#pragma unroll
                for (int nt = 0; nt < NT; ++nt)
                    acc[mt][nt] = __builtin_amdgcn_mfma_f32_16x16x32_bf16(af[mt], bf[nt], acc[mt][nt], 0, 0, 0);
        }
        __syncthreads();
    }

    const int fr = lane & 15, quad = lane >> 4;
    if (POOL) {
#pragma unroll
        for (int mt = 0; mt < 4; ++mt) {
            int pl = wm * 16 + mt * 4 + quad;
            int ob = rowO[pl];
#pragma unroll
            for (int nt = 0; nt < NT; ++nt) {
                int col = wn * (NT * 16) + nt * 16 + fr;
                float sc = scl[col], sh = sft[col];
                f32x4 a = acc[mt][nt];
                float v0 = a[0] * sc + sh, v1 = a[1] * sc + sh;
                float v2 = a[2] * sc + sh, v3 = a[3] * sc + sh;
                float mx = fmaxf(fmaxf(v0, v1), fmaxf(v2, v3));
                out[(size_t)ob + col] = f2b(fmaxf(mx, 0.f));
            }
        }
    } else {
#pragma unroll
        for (int mt = 0; mt < 4; ++mt) {
            int rb = wm * 64 + mt * 16 + quad * 4;
            int o0 = rowO[rb], o1 = rowO[rb + 1], o2 = rowO[rb + 2], o3 = rowO[rb + 3];
#pragma unroll
            for (int nt = 0; nt < NT; ++nt) {
                int col = wn * (NT * 16) + nt * 16 + fr;
                float sc = scl[col], sh = sft[col];
                f32x4 a = acc[mt][nt];
                out[(size_t)o0 + col] = f2b(fmaxf(a[0] * sc + sh, 0.f));
                out[(size_t)o1 + col] = f2b(fmaxf(a[1] * sc + sh, 0.f));
                out[(size_t)o2 + col] = f2b(fmaxf(a[2] * sc + sh, 0.f));
                out[(size_t)o3 + col] = f2b(fmaxf(a[3] * sc + sh, 0.f));
            }
        }
    }
}

// ---------------- conv34 v3: per-image fused conv3+conv4+pool ----------------
// Same structure as v2 (row-major M, conflict-free XOR swizzle, nt=8, pool via
// LDS) but spill-proofed: no min-occupancy launch bound (512-reg budget) and
// unroll-1 tap loops so the compiler cannot hoist B-load pipelines across 36
// unrolled steps (R8's 1.1GB scratch traffic).
__global__ __launch_bounds__(256)
void conv34(const u16* __restrict__ act2p, const u16* __restrict__ b3p, const u16* __restrict__ b4p,
            const float* __restrict__ b3, const float* __restrict__ g3, const float* __restrict__ be3,
            const float* __restrict__ m3, const float* __restrict__ v3,
            const float* __restrict__ b4, const float* __restrict__ g4, const float* __restrict__ be4,
            const float* __restrict__ m4, const float* __restrict__ v4,
            u16* __restrict__ out) {
    __shared__ __align__(16) u16 Xs[32768];   // 64KB: X2 [0,32K) then X3/X4 [0,64K)

    const int tid = threadIdx.x;
    const int n = blockIdx.x;
    const int w = tid >> 6, lane = tid & 63;
    const int fr = lane & 15, quad = lane >> 4;
    char* X = (char*)Xs;

    // phase A: stage X2 (256 rows x 128B, chunk c at pos c^(r&7))
    {
        const uint4* src = (const uint4*)(act2p + (size_t)n * 16384);
#pragma unroll
        for (int it = 0; it < 8; ++it) {
            int i = it * 256 + tid;
            int r = i >> 3, c = i & 7;
            uint4 v = src[i];
            *(uint4*)(X + r * 128 + ((c ^ (r & 7)) << 4)) = v;
        }
    }
    __syncthreads();

    const int mb = w * 64 + fr;   // wave's A-row base (+ mt*16)
    f32x4 acc[4][8];
#pragma unroll
    for (int a = 0; a < 4; ++a)
#pragma unroll
        for (int b = 0; b < 8; ++b) acc[a][b] = (f32x4){0.f, 0.f, 0.f, 0.f};

    // phase B: conv3, K=576 (9 taps x 2 halves), barrier-free
    const char* B3 = (const char*)b3p;
#pragma unroll 1
    for (int tap = 0; tap < 9; ++tap) {
        const int off = (tap / 3 - 1) * 16 + (tap % 3 - 1);
        int r[4];
#pragma unroll
        for (int mt = 0; mt < 4; ++mt) r[mt] = (mb + mt * 16 + off) & 255;
#pragma unroll
        for (int h = 0; h < 2; ++h) {
            const int s = tap * 2 + h;
            bf16x8 af[4], bf[8];
#pragma unroll
            for (int mt = 0; mt < 4; ++mt) {
                int pos = (h * 4 + quad) ^ (r[mt] & 7);
                af[mt] = *(const bf16x8*)(X + r[mt] * 128 + pos * 16);
            }
#pragma unroll
            for (int nt = 0; nt < 8; ++nt)
                bf[nt] = *(const bf16x8*)(B3 + (size_t)((s * 8 + nt) * 64 + lane) * 16);
#pragma unroll
            for (int mt = 0; mt < 4; ++mt)
#pragma unroll
                for (int nt = 0; nt < 8; ++nt)
                    acc[mt][nt] = __builtin_amdgcn_mfma_f32_16x16x32_bf16(af[mt], bf[nt], acc[mt][nt], 0, 0, 0);
        }
    }
    __syncthreads();   // all X2 reads done; X3 (64KB) may overwrite

    // phase C: build X3 (256 rows x 256B, chunk c at pos c^(r&15)); borders zero
    {
        float scl3[8], sft3[8];
#pragma unroll
        for (int nt = 0; nt < 8; ++nt) {
            int c = nt * 16 + fr;
            float s = g3[c] * rsqrtf(v3[c] + BN_EPS);
            scl3[nt] = s;
            sft3[nt] = (b3[c] - m3[c]) * s + be3[c];
        }
        for (int t = tid; t < 960; t += 256) {
            int ch = t & 15, b = t >> 4;
            int m = (b < 16) ? b : (b < 32) ? 224 + b : (b < 46) ? (b - 31) * 16 : (b - 45) * 16 + 15;
            *(uint4*)(X + m * 256 + ((ch ^ (m & 15)) << 4)) = make_uint4(0, 0, 0, 0);
        }
#pragma unroll
        for (int mt = 0; mt < 4; ++mt) {
            int y = w * 4 + mt;
            if (y >= 1 && y <= 14) {
#pragma unroll
                for (int j = 0; j < 4; ++j) {
                    int x = quad * 4 + j;
                    if (x >= 1 && x <= 14) {
                        int m = y * 16 + x;
#pragma unroll
                        for (int nt = 0; nt < 8; ++nt) {
                            int col = nt * 16 + fr;
                            float v = fmaxf(acc[mt][nt][j] * scl3[nt] + sft3[nt], 0.f);
                            *(u16*)(X + m * 256 + (((col >> 3) ^ (m & 15)) << 4) + (col & 7) * 2) = f2b(v);
                        }
                    }
                }
            }
        }
    }
    __syncthreads();

    // phase D: conv4, K=1152 (9 taps x 4 quarters), barrier-free
#pragma unroll
    for (int a = 0; a < 4; ++a)
#pragma unroll
        for (int b = 0; b < 8; ++b) acc[a][b] = (f32x4){0.f, 0.f, 0.f, 0.f};
    const char* B4 = (const char*)b4p;
#pragma unroll 1
    for (int tap = 0; tap < 9; ++tap) {
        const int off = (tap / 3 - 1) * 16 + (tap % 3 - 1);
        int r[4];
#pragma unroll
        for (int mt = 0; mt < 4; ++mt) r[mt] = (mb + mt * 16 + off) & 255;
#pragma unroll
        for (int qr = 0; qr < 4; ++qr) {
            const int s = tap * 4 + qr;
            bf16x8 af[4], bf[8];
#pragma unroll
            for (int mt = 0; mt < 4; ++mt) {
                int pos = (qr * 4 + quad) ^ (r[mt] & 15);
                af[mt] = *(const bf16x8*)(X + r[mt] * 256 + pos * 16);
            }
#pragma unroll
            for (int nt = 0; nt < 8; ++nt)
                bf[nt] = *(const bf16x8*)(B4 + (size_t)((s * 8 + nt) * 64 + lane) * 16);
#pragma unroll
            for (int mt = 0; mt < 4; ++mt)
#pragma unroll
                for (int nt = 0; nt < 8; ++nt)
                    acc[mt][nt] = __builtin_amdgcn_mfma_f32_16x16x32_bf16(af[mt], bf[nt], acc[mt][nt], 0, 0, 0);
        }
    }
    __syncthreads();   // X3 reads done; reuse as X4

    // phase E: write post-BN-ReLU conv4 (all rows; junk never read by pool)
    {
        float scl4[8], sft4[8];
#pragma unroll
        for (int nt = 0; nt < 8; ++nt) {
            int c = nt * 16 + fr;
            float s = g4[c] * rsqrtf(v4[c] + BN_EPS);
            scl4[nt] = s;
            sft4[nt] = (b4[c] - m4[c]) * s + be4[c];
        }
#pragma unroll
        for (int mt = 0; mt < 4; ++mt) {
#pragma unroll
            for (int j = 0; j < 4; ++j) {
                int m = w * 64 + mt * 16 + quad * 4 + j;
#pragma unroll
                for (int nt = 0; nt < 8; ++nt) {
                    int col = nt * 16 + fr;
                    float v = fmaxf(acc[mt][nt][j] * scl4[nt] + sft4[nt], 0.f);
                    *(u16*)(X + m * 256 + (((col >> 3) ^ (m & 15)) << 4) + (col & 7) * 2) = f2b(v);
                }
            }
        }
    }
    __syncthreads();

    // pool phase: 49 px x 16 chunks; bf16 >= 0 so u16 compare == float compare
    for (int t = tid; t < 784; t += 256) {
        int ch = t & 15, p = t >> 4;
        int oy = p / 7, ox = p % 7;
        int r00 = (2 * oy + 1) * 16 + (2 * ox + 1);
        int r01 = r00 + 1, r10 = r00 + 16, r11 = r00 + 17;
        uint4 A0 = *(const uint4*)(X + r00 * 256 + ((ch ^ (r00 & 15)) << 4));
        uint4 A1 = *(const uint4*)(X + r01 * 256 + ((ch ^ (r01 & 15)) << 4));
        uint4 A2 = *(const uint4*)(X + r10 * 256 + ((ch ^ (r10 & 15)) << 4));
        uint4 A3 = *(const uint4*)(X + r11 * 256 + ((ch ^ (r11 & 15)) << 4));
        const u16* pa = (const u16*)&A0;
        const u16* pb = (const u16*)&A1;
        const u16* pc = (const u16*)&A2;
        const u16* pd = (const u16*)&A3;
        u16 o[8];
#pragma unroll
        for (int e = 0; e < 8; ++e)
            o[e] = (u16)max(max((int)pa[e], (int)pb[e]), max((int)pc[e], (int)pd[e]));
        *(uint4*)(out + ((size_t)n * 49 + p) * 128 + ch * 8) = *(const uint4*)o;
    }
}

// ---------------- fc1: split-K MFMA GEMM (LDS dbuf), atomicAdd f32 into f1 ----------------
__global__ __launch_bounds__(256)
void fc1gemm(const u16* __restrict__ A, const u16* __restrict__ Bq, float* __restrict__ out) {
    constexpr int K = 6272, KC = 896, S = KC / 64;
    __shared__ __align__(16) u16 Alds[2][128 * 32];
    __shared__ __align__(16) u16 Blds[2][128 * 32];
    const int tid = threadIdx.x;
    const int m0 = blockIdx.x * 128;
    const int n0 = blockIdx.y * 128;
    const int k0 = blockIdx.z * KC;
    const int chunkb = ((tid >> 4) & 3) * 16;
    const int rr = (tid >> 6) * 16 + (tid & 15);
    const char* Ag = (const char*)A;
    const char* Bg = (const char*)Bq;
    const int wave = tid >> 6, lane = tid & 63;
    const int wm = wave & 1, wn = wave >> 1;
    const int fr16 = lane * 16;
    f32x4 acc[4][4] = {};

    for (int s = 0; s < S; ++s) {
#pragma unroll
        for (int j = 0; j < 2; ++j) {
            int kb = (k0 + s * 64 + j * 32) * 2 + chunkb;
            char* Al = (char*)Alds[j];
            char* Bl = (char*)Blds[j];
#pragma unroll
            for (int r = 0; r < 2; ++r) {
                load16(Ag + (size_t)(m0 + r * 64 + rr) * K * 2 + kb, Al + r * 4096 + tid * 16);
                load16(Bg + (size_t)(n0 + r * 64 + rr) * K * 2 + kb, Bl + r * 4096 + tid * 16);
            }
        }
        __syncthreads();
#pragma unroll
        for (int j = 0; j < 2; ++j) {
            const char* Al = (const char*)Alds[j];
            const char* Bl = (const char*)Blds[j];
            bf16x8 af[4], bf[4];
#pragma unroll
            for (int mt = 0; mt < 4; ++mt)
                af[mt] = *(const bf16x8*)(Al + (wm * 4 + mt) * 1024 + fr16);
#pragma unroll
            for (int nt = 0; nt < 4; ++nt)
                bf[nt] = *(const bf16x8*)(Bl + (wn * 4 + nt) * 1024 + fr16);
#pragma unroll
            for (int mt = 0; mt < 4; ++mt)
#pragma unroll
                for (int nt = 0; nt < 4; ++nt)
                    acc[mt][nt] = __builtin_amdgcn_mfma_f32_16x16x32_bf16(af[mt], bf[nt], acc[mt][nt], 0, 0, 0);
        }
        __syncthreads();
    }
    const int fr = lane & 15, quad = lane >> 4;
#pragma unroll
    for (int mt = 0; mt < 4; ++mt) {
        int row = m0 + wm * 64 + mt * 16 + quad * 4;
#pragma unroll
        for (int nt = 0; nt < 4; ++nt) {
            int col = n0 + wn * 64 + nt * 16 + fr;
            f32x4 a = acc[mt][nt];
            atomicAdd(&out[(size_t)(row + 0) * 256 + col], a[0]);
            atomicAdd(&out[(size_t)(row + 1) * 256 + col], a[1]);
            atomicAdd(&out[(size_t)(row + 2) * 256 + col], a[2]);
            atomicAdd(&out[(size_t)(row + 3) * 256 + col], a[3]);
        }
    }
}

// ---------------- fc2 fp32 GEMM; applies fc1's BN+ReLU to A on load ----------------
__global__ __launch_bounds__(256)
void fc2_kernel(const float* __restrict__ A, const float* __restrict__ Bw,
                const float* __restrict__ bA, const float* __restrict__ gA,
                const float* __restrict__ beA, const float* __restrict__ mA,
                const float* __restrict__ vA,
                const float* __restrict__ bias, const float* __restrict__ gam,
                const float* __restrict__ bet, const float* __restrict__ mu,
                const float* __restrict__ var, float* __restrict__ out) {
    constexpr int Nn = 128, K = 256;
    __shared__ __align__(16) float As[16][68];
    __shared__ __align__(16) float Bs[16][68];
    __shared__ float sclA[256], sftA[256];
    const int tid = threadIdx.x;
    const int n0 = blockIdx.x * 64, m0 = blockIdx.y * 64;
    if (tid < 256) {
        float s = gA[tid] * rsqrtf(vA[tid] + BN_EPS);
        sclA[tid] = s;
        sftA[tid] = (bA[tid] - mA[tid]) * s + beA[tid];
    }
    const int tm = tid >> 4, tn = tid & 15;
    const int lr = tid >> 2, lk = (tid & 3) * 4;
    float acc[4][4] = {};
    __syncthreads();
    for (int k0 = 0; k0 < K; k0 += 16) {
        float4 av = *(const float4*)&A[(size_t)(m0 + lr) * K + k0 + lk];
        float4 bv = *(const float4*)&Bw[(size_t)(n0 + lr) * K + k0 + lk];
        As[lk + 0][lr] = fmaxf(av.x * sclA[k0 + lk + 0] + sftA[k0 + lk + 0], 0.f);
        As[lk + 1][lr] = fmaxf(av.y * sclA[k0 + lk + 1] + sftA[k0 + lk + 1], 0.f);
        As[lk + 2][lr] = fmaxf(av.z * sclA[k0 + lk + 2] + sftA[k0 + lk + 2], 0.f);
        As[lk + 3][lr] = fmaxf(av.w * sclA[k0 + lk + 3] + sftA[k0 + lk + 3], 0.f);
        Bs[lk + 0][lr] = bv.x; Bs[lk + 1][lr] = bv.y; Bs[lk + 2][lr] = bv.z; Bs[lk + 3][lr] = bv.w;
        __syncthreads();
#pragma unroll
        for (int k = 0; k < 16; ++k) {
            float4 a = *(const float4*)&As[k][tm * 4];
            float4 b = *(const float4*)&Bs[k][tn * 4];
            acc[0][0] += a.x * b.x; acc[0][1] += a.x * b.y; acc[0][2] += a.x * b.z; acc[0][3] += a.x * b.w;
            acc[1][0] += a.y * b.x; acc[1][1] += a.y * b.y; acc[1][2] += a.y * b.z; acc[1][3] += a.y * b.w;
            acc[2][0] += a.z * b.x; acc[2][1] += a.z * b.y; acc[2][2] += a.z * b.z; acc[2][3] += a.z * b.w;
            acc[3][0] += a.w * b.x; acc[3][1] += a.w * b.y; acc[3][2] += a.w * b.z; acc[3][3] += a.w * b.w;
        }
        __syncthreads();
    }
#pragma unroll
    for (int i = 0; i < 4; ++i) {
        int row = m0 + tm * 4 + i;
#pragma unroll
        for (int j = 0; j < 4; ++j) {
            int col = n0 + tn * 4 + j;
            float sc = gam[col] * rsqrtf(var[col] + BN_EPS);
            float v = (acc[i][j] + bias[col] - mu[col]) * sc + bet[col];
            out[(size_t)row * Nn + col] = fmaxf(v, 0.f);
        }
    }
}

__global__ __launch_bounds__(256)
void fc3_kernel(const float* __restrict__ A, const float* __restrict__ Bw,
                const float* __restrict__ bias, float* __restrict__ out) {
    int i = blockIdx.x * blockDim.x + threadIdx.x;
    if (i >= 1024 * 10) return;
    int n = i / 10, j = i % 10;
    const float4* a = (const float4*)&A[(size_t)n * 128];
    const float4* b = (const float4*)&Bw[(size_t)j * 128];
    float s = 0.f;
#pragma unroll
    for (int k = 0; k < 32; ++k) {
        float4 x = a[k], y = b[k];
        s += x.x * y.x + x.y * y.y + x.z * y.z + x.w * y.w;
    }
    out[i] = s + bias[j];
}

extern "C" void kernel_launch(void* const* d_in, const int* in_sizes, int n_in,
                              void* d_out, int out_size, void* d_ws, size_t ws_size,
                              hipStream_t stream) {
    (void)in_sizes; (void)n_in; (void)out_size; (void)ws_size;
    const float* x   = (const float*)d_in[0];
    const float* w1  = (const float*)d_in[1];
    const float* w2  = (const float*)d_in[2];
    const float* w3  = (const float*)d_in[3];
    const float* w4  = (const float*)d_in[4];
    const float* wf1 = (const float*)d_in[5];
    const float* wf2 = (const float*)d_in[6];
    const float* wf3 = (const float*)d_in[7];
    auto P = [&](int i) { return (const float*)d_in[i]; };
    char* wsb = (char*)d_ws;
    float* sums = (float*)(wsb + O_SUMS);
    float* w1r  = (float*)(wsb + O_W1R);
    float* wf2q = (float*)(wsb + O_WF2Q);
    float* wf3q = (float*)(wsb + O_WF3Q);
    u16* bq2   = (u16*)(wsb + O_BQ2);
    u16* bq3p  = (u16*)(wsb + O_BQ3);
    u16* bq4p  = (u16*)(wsb + O_BQ4);
    u16* bqf1  = (u16*)(wsb + O_BQF1);
    float* f1  = (float*)(wsb + O_F1);
    float* f2  = (float*)(wsb + O_F2);
    u16* act1  = (u16*)(wsb + O_ACT1);
    u16* act2p = (u16*)(wsb + O_ACT2);
    u16* act4p = (u16*)(wsb + O_ACT4);

    // ternarization: 3 launches
    zero_sums<<<1, 64, 0, stream>>>(sums);
    absmean_all<<<226, 256, 0, stream>>>(w1, w2, w3, w4, wf1, wf2, wf3, sums);
    tern_all<<<634, 256, 0, stream>>>(w1, w2, w3, w4, wf1, wf2, wf3, sums,
                                      w1r, bq2, bq3p, bq4p, bqf1, wf2q, wf3q);

    // border zeros + f1 zero (independent)
    border_zero<32, 30, 28><<<(1024 * 116 * 4 + 255) / 256, 256, 0, stream>>>(act1);
    border_zero<64, 16, 14><<<(1024 * 60 * 8 + 255) / 256, 256, 0, stream>>>(act2p);
    zero_f1<<<256, 256, 0, stream>>>(f1);

    // conv1 -> act1 (pad30 interior)
    conv1_direct<<<1024, 256, 0, stream>>>(x, w1r, P(8), P(9), P(10), P(11), P(12), act1);
    // conv2 + fused pool -> act2p (pad16 C=64 interior)
    convgemm<32, 64, 28, 30, 1, true, true><<<6272, 256, 0, stream>>>(
        act1, bq2, P(13), P(14), P(15), P(16), P(17), act2p);
    // fused conv3+conv4+pool -> act4p [1024*49][128]
    conv34<<<1024, 256, 0, stream>>>(
        act2p, bq3p, bq4p,
        P(18), P(19), P(20), P(21), P(22),
        P(23), P(24), P(25), P(26), P(27), act4p);
    // fc1 split-K (7 chunks of 896) -> atomic f32 into f1
    fc1gemm<<<dim3(8, 2, 7), 256, 0, stream>>>(act4p, bqf1, f1);
    // fc2 (applies fc1 BN+ReLU on A-load) -> f2
    fc2_kernel<<<dim3(2, 16), 256, 0, stream>>>(
        f1, wf2q, P(28), P(29), P(30), P(31), P(32),
        P(33), P(34), P(35), P(36), P(37), f2);
    // fc3 -> logits
    fc3_kernel<<<40, 256, 0, stream>>>(f2, wf3q, P(38), (float*)d_out);
}

// Round 10
// 432.830 us; speedup vs baseline: 1.6511x; 1.0241x over previous
//
#include <hip/hip_runtime.h>
#include <hip/hip_bf16.h>

#define BN_EPS 1e-5f

typedef __attribute__((ext_vector_type(8))) short bf16x8;
typedef __attribute__((ext_vector_type(4))) float f32x4;
typedef unsigned short u16;
typedef unsigned int u32;

__device__ __forceinline__ void load16(const void* g, void* l) {
    __builtin_amdgcn_global_load_lds((const __attribute__((address_space(1))) void*)g,
                                     (__attribute__((address_space(3))) void*)l, 16, 0, 0);
}
__device__ __forceinline__ u16 f2b(float v) {
    __hip_bfloat16 h = __float2bfloat16(v);
    return *reinterpret_cast<u16*>(&h);
}
__device__ __forceinline__ float ternq(float x, float d) {
    return (fabsf(x) > d) ? (x > 0.f ? 1.f : -1.f) : 0.f;
}

// ---------------- ws layout (BYTE offsets) ----------------
constexpr size_t ALGN(size_t x) { return (x + 255) & ~(size_t)255; }
constexpr size_t O_SUMS = 0;                                   // 8 f32
constexpr size_t O_W1R  = 256;                                 // 288 f32
constexpr size_t O_WF2Q = ALGN(O_W1R + 288 * 4);               // 32768 f32
constexpr size_t O_WF3Q = ALGN(O_WF2Q + 32768 * 4);            // 1280 f32
constexpr size_t O_BQ2  = ALGN(O_WF3Q + 1280 * 4);             // [64][288] bf16 (frag layout)
constexpr size_t O_BQ3  = ALGN(O_BQ2 + 64 * 288 * 2);          // B3' primed [18][8][64][8] bf16
constexpr size_t O_BQ4  = ALGN(O_BQ3 + 128 * 576 * 2);         // B4' primed [36][8][64][8] bf16
constexpr size_t O_BQF1 = ALGN(O_BQ4 + 128 * 1152 * 2);        // [256][6272] bf16
constexpr size_t O_F1   = ALGN(O_BQF1 + (size_t)256 * 6272 * 2);  // [1024][256] f32
constexpr size_t O_F2   = ALGN(O_F1 + 1024 * 256 * 4);         // [1024][128] f32
constexpr size_t O_ACT1 = ALGN(O_F2 + 1024 * 128 * 4);         // pad30 C=32 bf16
constexpr size_t O_ACT2 = ALGN(O_ACT1 + (size_t)1024 * 900 * 32 * 2);  // pad16 C=64
constexpr size_t O_ACT3 = ALGN(O_ACT2 + (size_t)1024 * 256 * 64 * 2);  // (unused)
constexpr size_t O_ACT4 = ALGN(O_ACT3 + (size_t)1024 * 256 * 128 * 2); // [1024*49][128]

// ---------------- ternarization (merged) ----------------
__global__ void zero_sums(float* s) { if (threadIdx.x < 8) s[threadIdx.x] = 0.f; }

__device__ void absmean_seg(const float* __restrict__ w, int n4, float* __restrict__ sum,
                            int b0, int nb) {
    __shared__ float sm[256];
    float s = 0.f;
    for (int i = b0 * 256 + threadIdx.x; i < n4; i += nb * 256) {
        float4 v = ((const float4*)w)[i];
        s += fabsf(v.x) + fabsf(v.y) + fabsf(v.z) + fabsf(v.w);
    }
    sm[threadIdx.x] = s;
    __syncthreads();
    for (int o = 128; o > 0; o >>= 1) {
        if (threadIdx.x < o) sm[threadIdx.x] += sm[threadIdx.x + o];
        __syncthreads();
    }
    if (threadIdx.x == 0) atomicAdd(sum, sm[0]);
}

__global__ void absmean_all(const float* w1, const float* w2, const float* w3, const float* w4,
                            const float* wf1, const float* wf2, const float* wf3, float* sums) {
    int b = blockIdx.x;
    if (b < 160)      absmean_seg(wf1, 401408, sums + 4, b, 160);
    else if (b < 192) absmean_seg(w4, 36864, sums + 3, b - 160, 32);
    else if (b < 208) absmean_seg(w3, 18432, sums + 2, b - 192, 16);
    else if (b < 216) absmean_seg(w2, 4608, sums + 1, b - 208, 8);
    else if (b < 224) absmean_seg(wf2, 8192, sums + 5, b - 216, 8);
    else if (b < 225) absmean_seg(w1, 72, sums + 0, 0, 1);
    else              absmean_seg(wf3, 320, sums + 6, 0, 1);
}

// conv2 weights: src [co][ci][9] -> frag layout [co][tap*CIN+ci]
__device__ void tern_conv_seg(const float* __restrict__ w, float d, u16* __restrict__ bq,
                              int COUT, int CIN, int b0, int nb) {
    int N = COUT * CIN * 9;
    for (int i = b0 * 256 + threadIdx.x; i < N; i += nb * 256) {
        float q = ternq(w[i], d);
        int co = i / (CIN * 9), r = i % (CIN * 9);
        int ci = r / 9, tap = r % 9;
        bq[(size_t)co * CIN * 9 + tap * CIN + ci] = f2b(q);
    }
}
// conv3/4 weights -> primed coalesced layout [s][nt][lane][8] (COUT=128)
__device__ void tern_conv_prime_seg(const float* __restrict__ w, float d, u16* __restrict__ bqp,
                                    int CIN, int b0, int nb) {
    int N = 128 * CIN * 9;
    for (int i = b0 * 256 + threadIdx.x; i < N; i += nb * 256) {
        float q = ternq(w[i], d);
        int co = i / (CIN * 9), r = i % (CIN * 9);
        int ci = r / 9, tap = r % 9;
        int k = tap * CIN + ci;
        int s = k >> 5, qd = (k & 31) >> 3, e = k & 7;
        int lane = qd * 16 + (co & 15), nt = co >> 4;
        bqp[((size_t)(s * 8 + nt) * 64 + lane) * 8 + e] = f2b(q);
    }
}
__device__ void tern_f32_seg(const float* __restrict__ w, float d, float* __restrict__ wq,
                             int N, int b0, int nb) {
    for (int i = b0 * 256 + threadIdx.x; i < N; i += nb * 256) wq[i] = ternq(w[i], d);
}

__global__ void tern_all(const float* w1, const float* w2, const float* w3, const float* w4,
                         const float* wf1, const float* wf2, const float* wf3,
                         const float* __restrict__ sums,
                         float* w1r, u16* bq2, u16* bq3p, u16* bq4p, u16* bqf1,
                         float* wf2q, float* wf3q) {
    int b = blockIdx.x;
    if (b < 1) {
        tern_f32_seg(w1, 0.7f * sums[0] / 288.f, w1r, 288, 0, 1);
    } else if (b < 9) {
        tern_conv_seg(w2, 0.7f * sums[1] / 18432.f, bq2, 64, 32, b - 1, 8);
    } else if (b < 41) {
        tern_conv_prime_seg(w3, 0.7f * sums[2] / 73728.f, bq3p, 64, b - 9, 32);
    } else if (b < 105) {
        tern_conv_prime_seg(w4, 0.7f * sums[3] / 147456.f, bq4p, 128, b - 41, 64);
    } else if (b < 617) {
        // wf1 [256][6272], k=c*49+s -> bf16 [256][s*128+c]
        float d = 0.7f * sums[4] / 1605632.f;
        for (int i = (b - 105) * 256 + threadIdx.x; i < 1605632; i += 512 * 256) {
            float q = ternq(wf1[i], d);
            int j = i / 6272, k = i % 6272;
            int c = k / 49, s = k % 49;
            bqf1[(size_t)j * 6272 + s * 128 + c] = f2b(q);
        }
    } else if (b < 633) {
        tern_f32_seg(wf2, 0.7f * sums[5] / 32768.f, wf2q, 32768, b - 617, 16);
    } else {
        tern_f32_seg(wf3, 0.7f * sums[6] / 1280.f, wf3q, 1280, 0, 1);
    }
}

__global__ void zero_f1(float* f1) {
    ((float4*)f1)[blockIdx.x * 256 + threadIdx.x] = make_float4(0.f, 0.f, 0.f, 0.f);
}

// ---------------- conv1 direct (Cin=1) -> pad30 NHWC bf16 ----------------
__global__ __launch_bounds__(256)
void conv1_direct(const float* __restrict__ x, const float* __restrict__ w1r,
                  const float* __restrict__ bias, const float* __restrict__ gam,
                  const float* __restrict__ bet, const float* __restrict__ mu,
                  const float* __restrict__ var, u16* __restrict__ out) {
    __shared__ float xs[784];
    __shared__ float wsh[288];
    __shared__ float scl[32], sft[32];
    const int n = blockIdx.x, tid = threadIdx.x;
    for (int i = tid; i < 784; i += 256) xs[i] = x[(size_t)n * 784 + i];
    for (int i = tid; i < 288; i += 256) wsh[i] = w1r[i];
    if (tid < 32) {
        float s = gam[tid] * rsqrtf(var[tid] + BN_EPS);
        scl[tid] = s;
        sft[tid] = (bias[tid] - mu[tid]) * s + bet[tid];
    }
    __syncthreads();
    for (int p = tid; p < 784; p += 256) {
        int y = p / 28, xx = p % 28;
        float patch[9];
#pragma unroll
        for (int dy = 0; dy < 3; ++dy)
#pragma unroll
            for (int dx = 0; dx < 3; ++dx) {
                int gy = y + dy - 1, gx = xx + dx - 1;
                patch[dy * 3 + dx] = (gy >= 0 && gy < 28 && gx >= 0 && gx < 28) ? xs[gy * 28 + gx] : 0.f;
            }
        u32 pk[16];
#pragma unroll
        for (int co = 0; co < 32; co += 2) {
            float s0 = 0.f, s1 = 0.f;
#pragma unroll
            for (int t = 0; t < 9; ++t) {
                s0 += wsh[co * 9 + t] * patch[t];
                s1 += wsh[(co + 1) * 9 + t] * patch[t];
            }
            float v0 = fmaxf(s0 * scl[co] + sft[co], 0.f);
            float v1 = fmaxf(s1 * scl[co + 1] + sft[co + 1], 0.f);
            pk[co >> 1] = ((u32)f2b(v1) << 16) | (u32)f2b(v0);
        }
        size_t base = ((size_t)(n * 30 + y + 1) * 30 + (xx + 1)) * 32;
#pragma unroll
        for (int q = 0; q < 4; ++q) ((uint4*)(out + base))[q] = ((uint4*)pk)[q];
    }
}

// ---------------- border zero for padded NHWC buffers ----------------
template<int C, int HP, int HV>
__global__ void border_zero(u16* __restrict__ buf) {
    constexpr int NB = 2 * HP + 2 * HV;
    constexpr int CG = C / 8;
    int i = blockIdx.x * blockDim.x + threadIdx.x;
    if (i >= 1024 * NB * CG) return;
    int cg = i % CG, r = i / CG;
    int b = r % NB, n = r / NB;
    int py, px;
    if (b < HP)               { py = 0;                  px = b; }
    else if (b < 2 * HP)      { py = HP - 1;             px = b - HP; }
    else if (b < 2 * HP + HV) { py = b - 2 * HP + 1;     px = 0; }
    else                      { py = b - 2 * HP - HV + 1; px = HP - 1; }
    size_t off = ((size_t)(n * HP + py) * HP + px) * C + cg * 8;
    *(uint4*)(buf + off) = make_uint4(0, 0, 0, 0);
}

// ---------------- conv2: R3-style implicit GEMM, frag-major LDS, fused pool ----------------
template<int CIN, int BN, int HV, int HP, int G, bool POOL, bool PADOUT>
__global__ __launch_bounds__(256)
void convgemm(const u16* __restrict__ act, const u16* __restrict__ bq,
              const float* __restrict__ bias, const float* __restrict__ gam,
              const float* __restrict__ bet, const float* __restrict__ mu,
              const float* __restrict__ var, u16* __restrict__ out) {
    constexpr int BM = 128;
    constexpr int K = 9 * CIN;
    constexpr int S = K / (32 * G);
    constexpr int TPC = CIN / 32;
    constexpr int NT = BN / 32;
    constexpr int RB = BN / 64;
    constexpr int HO = HV / 2;
    constexpr int PP = POOL ? HO * HO : HV * HV;

    __shared__ __align__(16) u16 Alds[G][BM * 32];
    __shared__ __align__(16) u16 Blds[G][BN * 32];
    __shared__ int rowA[BM];
    __shared__ int rowO[BM];
    __shared__ float scl[BN], sft[BN];

    const int tid = threadIdx.x;
    const int m0 = blockIdx.x * BM;

    for (int t = tid; t < BM; t += 256) {
        int base;
        if (POOL) {
            int p = (m0 >> 2) + (t >> 2), q = t & 3;
            int n = p / PP, rr = p % PP;
            int oy = rr / HO, ox = rr % HO;
            int y = oy * 2 + (q >> 1), x = ox * 2 + (q & 1);
            base = ((n * HP + y) * HP + x) * CIN;
        } else {
            int m = m0 + t;
            int n = m / PP, rr = m % PP;
            int y = rr / HV, x = rr % HV;
            base = ((n * HP + y) * HP + x) * CIN;
        }
        rowA[t] = base;
    }
    if (POOL) {
        if (tid < 32) {
            int p = (m0 >> 2) + tid;
            int n = p / PP, rr = p % PP;
            int oy = rr / HO, ox = rr % HO;
            rowO[tid] = PADOUT ? ((n * 16 + oy + 1) * 16 + ox + 1) * BN : p * BN;
        }
    } else {
        for (int t = tid; t < BM; t += 256) {
            int m = m0 + t;
            int n = m / PP, rr = m % PP;
            int y = rr / HV, x = rr % HV;
            rowO[t] = PADOUT ? ((n * 16 + y + 1) * 16 + x + 1) * BN : m * BN;
        }
    }
    if (tid < BN) {
        float s = gam[tid] * rsqrtf(var[tid] + BN_EPS);
        scl[tid] = s;
        sft[tid] = (bias[tid] - mu[tid]) * s + bet[tid];
    }
    __syncthreads();

    int arow[2];
    arow[0] = rowA[(tid >> 6) * 16 + (tid & 15)];
    arow[1] = rowA[64 + (tid >> 6) * 16 + (tid & 15)];
    const int chunkb = ((tid >> 4) & 3) * 16;
    const int bco = (tid >> 6) * 16 + (tid & 15);
    const char* actb = (const char*)act;
    const char* bqb  = (const char*)bq;

    const int wave = tid >> 6, lane = tid & 63;
    const int wm = wave & 1, wn = wave >> 1;
    const int fr16 = lane * 16;

    f32x4 acc[4][NT] = {};

    for (int s = 0; s < S; ++s) {
#pragma unroll
        for (int j = 0; j < G; ++j) {
            int g = s * G + j;
            int tap = g / TPC, cio = (g % TPC) * 32;
            int dy = tap / 3, dx = tap % 3;
            int toffb = ((dy * HP + dx) * CIN + cio) * 2;
            char* Al = (char*)Alds[j];
#pragma unroll
            for (int r = 0; r < 2; ++r)
                load16(actb + (size_t)arow[r] * 2 + toffb + chunkb, Al + r * 4096 + tid * 16);
            char* Bl = (char*)Blds[j];
            int bkob = g * 64 + chunkb;
#pragma unroll
            for (int r = 0; r < RB; ++r)
                load16(bqb + (size_t)(r * 64 + bco) * K * 2 + bkob, Bl + r * 4096 + tid * 16);
        }
        __syncthreads();
#pragma unroll
        for (int j = 0; j < G; ++j) {
            const char* Al = (const char*)Alds[j];
            const char* Bl = (const char*)Blds[j];
            bf16x8 af[4], bf[NT];
#pragma unroll
            for (int mt = 0; mt < 4; ++mt)
                af[mt] = *(const bf16x8*)(Al + (wm * 4 + mt) * 1024 + fr16);
#pragma unroll
            for (int nt = 0; nt < NT; ++nt)
                bf[nt] = *(const bf16x8*)(Bl + (wn * NT + nt) * 1024 + fr16);
#pragma unroll
            for (int mt = 0; mt < 4; ++mt)
#pragma unroll
                for (int nt = 0; nt < NT; ++nt)
                    acc[mt][nt] = __builtin_amdgcn_mfma_f32_16x16x32_bf16(af[mt], bf[nt], acc[mt][nt], 0, 0, 0);
        }
        __syncthreads();
    }

    const int fr = lane & 15, quad = lane >> 4;
    if (POOL) {
#pragma unroll
        for (int mt = 0; mt < 4; ++mt) {
            int pl = wm * 16 + mt * 4 + quad;
            int ob = rowO[pl];
#pragma unroll
            for (int nt = 0; nt < NT; ++nt) {
                int col = wn * (NT * 16) + nt * 16 + fr;
                float sc = scl[col], sh = sft[col];
                f32x4 a = acc[mt][nt];
                float v0 = a[0] * sc + sh, v1 = a[1] * sc + sh;
                float v2 = a[2] * sc + sh, v3 = a[3] * sc + sh;
                float mx = fmaxf(fmaxf(v0, v1), fmaxf(v2, v3));
                out[(size_t)ob + col] = f2b(fmaxf(mx, 0.f));
            }
        }
    } else {
#pragma unroll
        for (int mt = 0; mt < 4; ++mt) {
            int rb = wm * 64 + mt * 16 + quad * 4;
            int o0 = rowO[rb], o1 = rowO[rb + 1], o2 = rowO[rb + 2], o3 = rowO[rb + 3];
#pragma unroll
            for (int nt = 0; nt < NT; ++nt) {
                int col = wn * (NT * 16) + nt * 16 + fr;
                float sc = scl[col], sh = sft[col];
                f32x4 a = acc[mt][nt];
                out[(size_t)o0 + col] = f2b(fmaxf(a[0] * sc + sh, 0.f));
                out[(size_t)o1 + col] = f2b(fmaxf(a[1] * sc + sh, 0.f));
                out[(size_t)o2 + col] = f2b(fmaxf(a[2] * sc + sh, 0.f));
                out[(size_t)o3 + col] = f2b(fmaxf(a[3] * sc + sh, 0.f));
            }
        }
    }
}

// ---------------- conv34 v4: per-image fused conv3+conv4+pool ----------------
// Padded-stride LDS (no XOR): X2 rows at stride 144B, X3/X4 at 272B (stride ≡ 4
// mod 32 banks -> same even bank spread as the measured-zero-conflict frag-major
// layouts). Physical arena covers logical rows -17..272 so tap reads need no
// wrap/clamp; out-of-range rows are junk feeding only discarded outputs. A-read
// address = loop-invariant base[mt] + per-tap offset -> ~8 VALU/tap vs R9's
// ~75/step of XOR recompute. Row-split waves, nt=8, unroll-1 taps (no spill).
__global__ __launch_bounds__(256)
void conv34(const u16* __restrict__ act2p, const u16* __restrict__ b3p, const u16* __restrict__ b4p,
            const float* __restrict__ b3, const float* __restrict__ g3, const float* __restrict__ be3,
            const float* __restrict__ m3, const float* __restrict__ v3,
            const float* __restrict__ b4, const float* __restrict__ g4, const float* __restrict__ be4,
            const float* __restrict__ m4, const float* __restrict__ v4,
            u16* __restrict__ out) {
    __shared__ __align__(16) char X[290 * 272];   // 78880 B; X2 uses first 290*144

    const int tid = threadIdx.x;
    const int n = blockIdx.x;
    const int w = tid >> 6, lane = tid & 63;
    const int fr = lane & 15, quad = lane >> 4;

    // phase A: stage X2 rows 0..255 (stride 144B, 8 chunks linear)
    {
        const uint4* src = (const uint4*)(act2p + (size_t)n * 16384);
#pragma unroll
        for (int it = 0; it < 8; ++it) {
            int i = it * 256 + tid;
            int r = i >> 3, c = i & 7;
            *(uint4*)(X + (r + 17) * 144 + c * 16) = src[i];
        }
    }
    __syncthreads();

    const int mb = w * 64 + fr;   // wave's A-row base (+ mt*16)
    f32x4 acc[4][8] = {};

    // phase B: conv3, K=576 (9 taps x 2 halves), barrier-free
    {
        const char* B3 = (const char*)b3p;
        int ab[4];
#pragma unroll
        for (int mt = 0; mt < 4; ++mt) ab[mt] = (mb + mt * 16) * 144 + quad * 16;
#pragma unroll 1
        for (int tap = 0; tap < 9; ++tap) {
            const int ib = ((tap / 3) * 16 + (tap % 3)) * 144;   // (off+17)*144
#pragma unroll
            for (int h = 0; h < 2; ++h) {
                const int s = tap * 2 + h;
                bf16x8 af[4], bf[8];
#pragma unroll
                for (int mt = 0; mt < 4; ++mt)
                    af[mt] = *(const bf16x8*)(X + ab[mt] + ib + h * 64);
#pragma unroll
                for (int nt = 0; nt < 8; ++nt)
                    bf[nt] = *(const bf16x8*)(B3 + (size_t)((s * 8 + nt) * 64 + lane) * 16);
#pragma unroll
                for (int mt = 0; mt < 4; ++mt)
#pragma unroll
                    for (int nt = 0; nt < 8; ++nt)
                        acc[mt][nt] = __builtin_amdgcn_mfma_f32_16x16x32_bf16(af[mt], bf[nt], acc[mt][nt], 0, 0, 0);
            }
        }
    }
    __syncthreads();   // all X2 reads done; X3 may overwrite

    // phase C: build X3 (stride 272B, cols linear at col*2); borders zero
    {
        float scl3[8], sft3[8];
#pragma unroll
        for (int nt = 0; nt < 8; ++nt) {
            int c = nt * 16 + fr;
            float s = g3[c] * rsqrtf(v3[c] + BN_EPS);
            scl3[nt] = s;
            sft3[nt] = (b3[c] - m3[c]) * s + be3[c];
        }
        for (int t = tid; t < 960; t += 256) {
            int ch = t & 15, b = t >> 4;
            int m = (b < 16) ? b : (b < 32) ? 224 + b : (b < 46) ? (b - 31) * 16 : (b - 45) * 16 + 15;
            *(uint4*)(X + (m + 17) * 272 + ch * 16) = make_uint4(0, 0, 0, 0);
        }
#pragma unroll
        for (int mt = 0; mt < 4; ++mt) {
            int y = w * 4 + mt;
            if (y >= 1 && y <= 14) {
#pragma unroll
                for (int j = 0; j < 4; ++j) {
                    int x = quad * 4 + j;
                    if (x >= 1 && x <= 14) {
                        char* row = X + (y * 16 + x + 17) * 272;
#pragma unroll
                        for (int nt = 0; nt < 8; ++nt) {
                            int col = nt * 16 + fr;
                            float v = fmaxf(acc[mt][nt][j] * scl3[nt] + sft3[nt], 0.f);
                            *(u16*)(row + col * 2) = f2b(v);
                        }
                    }
                }
            }
        }
    }
    __syncthreads();

    // phase D: conv4, K=1152 (9 taps x 4 quarters), barrier-free
#pragma unroll
    for (int a = 0; a < 4; ++a)
#pragma unroll
        for (int b = 0; b < 8; ++b) acc[a][b] = (f32x4){0.f, 0.f, 0.f, 0.f};
    {
        const char* B4 = (const char*)b4p;
        int ab[4];
#pragma unroll
        for (int mt = 0; mt < 4; ++mt) ab[mt] = (mb + mt * 16) * 272 + quad * 16;
#pragma unroll 1
        for (int tap = 0; tap < 9; ++tap) {
            const int ib = ((tap / 3) * 16 + (tap % 3)) * 272;   // (off+17)*272
#pragma unroll
            for (int qr = 0; qr < 4; ++qr) {
                const int s = tap * 4 + qr;
                bf16x8 af[4], bf[8];
#pragma unroll
                for (int mt = 0; mt < 4; ++mt)
                    af[mt] = *(const bf16x8*)(X + ab[mt] + ib + qr * 64);
#pragma unroll
                for (int nt = 0; nt < 8; ++nt)
                    bf[nt] = *(const bf16x8*)(B4 + (size_t)((s * 8 + nt) * 64 + lane) * 16);
#pragma unroll
                for (int mt = 0; mt < 4; ++mt)
#pragma unroll
                    for (int nt = 0; nt < 8; ++nt)
                        acc[mt][nt] = __builtin_amdgcn_mfma_f32_16x16x32_bf16(af[mt], bf[nt], acc[mt][nt], 0, 0, 0);
            }
        }
    }
    __syncthreads();   // X3 reads done; reuse as X4

    // phase E: write post-BN-ReLU conv4 (all rows; junk never read by pool)
    {
        float scl4[8], sft4[8];
#pragma unroll
        for (int nt = 0; nt < 8; ++nt) {
            int c = nt * 16 + fr;
            float s = g4[c] * rsqrtf(v4[c] + BN_EPS);
            scl4[nt] = s;
            sft4[nt] = (b4[c] - m4[c]) * s + be4[c];
        }
#pragma unroll
        for (int mt = 0; mt < 4; ++mt) {
#pragma unroll
            for (int j = 0; j < 4; ++j) {
                char* row = X + (w * 64 + mt * 16 + quad * 4 + j + 17) * 272;
#pragma unroll
                for (int nt = 0; nt < 8; ++nt) {
                    int col = nt * 16 + fr;
                    float v = fmaxf(acc[mt][nt][j] * scl4[nt] + sft4[nt], 0.f);
                    *(u16*)(row + col * 2) = f2b(v);
                }
            }
        }
    }
    __syncthreads();

    // pool phase: 49 px x 16 chunks; bf16 >= 0 so u16 compare == float compare
    for (int t = tid; t < 784; t += 256) {
        int ch = t & 15, p = t >> 4;
        int oy = p / 7, ox = p % 7;
        int r00 = (2 * oy + 1) * 16 + (2 * ox + 1) + 17;
        uint4 A0 = *(const uint4*)(X + (r00) * 272 + ch * 16);
        uint4 A1 = *(const uint4*)(X + (r00 + 1) * 272 + ch * 16);
        uint4 A2 = *(const uint4*)(X + (r00 + 16) * 272 + ch * 16);
        uint4 A3 = *(const uint4*)(X + (r00 + 17) * 272 + ch * 16);
        const u16* pa = (const u16*)&A0;
        const u16* pb = (const u16*)&A1;
        const u16* pc = (const u16*)&A2;
        const u16* pd = (const u16*)&A3;
        u16 o[8];
#pragma unroll
        for (int e = 0; e < 8; ++e)
            o[e] = (u16)max(max((int)pa[e], (int)pb[e]), max((int)pc[e], (int)pd[e]));
        *(uint4*)(out + ((size_t)n * 49 + p) * 128 + ch * 8) = *(const uint4*)o;
    }
}

// ---------------- fc1: split-K MFMA GEMM (LDS dbuf), atomicAdd f32 into f1 ----------------
__global__ __launch_bounds__(256)
void fc1gemm(const u16* __restrict__ A, const u16* __restrict__ Bq, float* __restrict__ out) {
    constexpr int K = 6272, KC = 896, S = KC / 64;
    __shared__ __align__(16) u16 Alds[2][128 * 32];
    __shared__ __align__(16) u16 Blds[2][128 * 32];
    const int tid = threadIdx.x;
    const int m0 = blockIdx.x * 128;
    const int n0 = blockIdx.y * 128;
    const int k0 = blockIdx.z * KC;
    const int chunkb = ((tid >> 4) & 3) * 16;
    const int rr = (tid >> 6) * 16 + (tid & 15);
    const char* Ag = (const char*)A;
    const char* Bg = (const char*)Bq;
    const int wave = tid >> 6, lane = tid & 63;
    const int wm = wave & 1, wn = wave >> 1;
    const int fr16 = lane * 16;
    f32x4 acc[4][4] = {};

    for (int s = 0; s < S; ++s) {
#pragma unroll
        for (int j = 0; j < 2; ++j) {
            int kb = (k0 + s * 64 + j * 32) * 2 + chunkb;
            char* Al = (char*)Alds[j];
            char* Bl = (char*)Blds[j];
#pragma unroll
            for (int r = 0; r < 2; ++r) {
                load16(Ag + (size_t)(m0 + r * 64 + rr) * K * 2 + kb, Al + r * 4096 + tid * 16);
                load16(Bg + (size_t)(n0 + r * 64 + rr) * K * 2 + kb, Bl + r * 4096 + tid * 16);
            }
        }
        __syncthreads();
#pragma unroll
        for (int j = 0; j < 2; ++j) {
            const char* Al = (const char*)Alds[j];
            const char* Bl = (const char*)Blds[j];
            bf16x8 af[4], bf[4];
#pragma unroll
            for (int mt = 0; mt < 4; ++mt)
                af[mt] = *(const bf16x8*)(Al + (wm * 4 + mt) * 1024 + fr16);
#pragma unroll
            for (int nt = 0; nt < 4; ++nt)
                bf[nt] = *(const bf16x8*)(Bl + (wn * 4 + nt) * 1024 + fr16);
#pragma unroll
            for (int mt = 0; mt < 4; ++mt)
#pragma unroll
                for (int nt = 0; nt < 4; ++nt)
                    acc[mt][nt] = __builtin_amdgcn_mfma_f32_16x16x32_bf16(af[mt], bf[nt], acc[mt][nt], 0, 0, 0);
        }
        __syncthreads();
    }
    const int fr = lane & 15, quad = lane >> 4;
#pragma unroll
    for (int mt = 0; mt < 4; ++mt) {
        int row = m0 + wm * 64 + mt * 16 + quad * 4;
#pragma unroll
        for (int nt = 0; nt < 4; ++nt) {
            int col = n0 + wn * 64 + nt * 16 + fr;
            f32x4 a = acc[mt][nt];
            atomicAdd(&out[(size_t)(row + 0) * 256 + col], a[0]);
            atomicAdd(&out[(size_t)(row + 1) * 256 + col], a[1]);
            atomicAdd(&out[(size_t)(row + 2) * 256 + col], a[2]);
            atomicAdd(&out[(size_t)(row + 3) * 256 + col], a[3]);
        }
    }
}

// ---------------- fc2 fp32 GEMM; applies fc1's BN+ReLU to A on load ----------------
__global__ __launch_bounds__(256)
void fc2_kernel(const float* __restrict__ A, const float* __restrict__ Bw,
                const float* __restrict__ bA, const float* __restrict__ gA,
                const float* __restrict__ beA, const float* __restrict__ mA,
                const float* __restrict__ vA,
                const float* __restrict__ bias, const float* __restrict__ gam,
                const float* __restrict__ bet, const float* __restrict__ mu,
                const float* __restrict__ var, float* __restrict__ out) {
    constexpr int Nn = 128, K = 256;
    __shared__ __align__(16) float As[16][68];
    __shared__ __align__(16) float Bs[16][68];
    __shared__ float sclA[256], sftA[256];
    const int tid = threadIdx.x;
    const int n0 = blockIdx.x * 64, m0 = blockIdx.y * 64;
    if (tid < 256) {
        float s = gA[tid] * rsqrtf(vA[tid] + BN_EPS);
        sclA[tid] = s;
        sftA[tid] = (bA[tid] - mA[tid]) * s + beA[tid];
    }
    const int tm = tid >> 4, tn = tid & 15;
    const int lr = tid >> 2, lk = (tid & 3) * 4;
    float acc[4][4] = {};
    __syncthreads();
    for (int k0 = 0; k0 < K; k0 += 16) {
        float4 av = *(const float4*)&A[(size_t)(m0 + lr) * K + k0 + lk];
        float4 bv = *(const float4*)&Bw[(size_t)(n0 + lr) * K + k0 + lk];
        As[lk + 0][lr] = fmaxf(av.x * sclA[k0 + lk + 0] + sftA[k0 + lk + 0], 0.f);
        As[lk + 1][lr] = fmaxf(av.y * sclA[k0 + lk + 1] + sftA[k0 + lk + 1], 0.f);
        As[lk + 2][lr] = fmaxf(av.z * sclA[k0 + lk + 2] + sftA[k0 + lk + 2], 0.f);
        As[lk + 3][lr] = fmaxf(av.w * sclA[k0 + lk + 3] + sftA[k0 + lk + 3], 0.f);
        Bs[lk + 0][lr] = bv.x; Bs[lk + 1][lr] = bv.y; Bs[lk + 2][lr] = bv.z; Bs[lk + 3][lr] = bv.w;
        __syncthreads();
#pragma unroll
        for (int k = 0; k < 16; ++k) {
            float4 a = *(const float4*)&As[k][tm * 4];
            float4 b = *(const float4*)&Bs[k][tn * 4];
            acc[0][0] += a.x * b.x; acc[0][1] += a.x * b.y; acc[0][2] += a.x * b.z; acc[0][3] += a.x * b.w;
            acc[1][0] += a.y * b.x; acc[1][1] += a.y * b.y; acc[1][2] += a.y * b.z; acc[1][3] += a.y * b.w;
            acc[2][0] += a.z * b.x; acc[2][1] += a.z * b.y; acc[2][2] += a.z * b.z; acc[2][3] += a.z * b.w;
            acc[3][0] += a.w * b.x; acc[3][1] += a.w * b.y; acc[3][2] += a.w * b.z; acc[3][3] += a.w * b.w;
        }
        __syncthreads();
    }
#pragma unroll
    for (int i = 0; i < 4; ++i) {
        int row = m0 + tm * 4 + i;
#pragma unroll
        for (int j = 0; j < 4; ++j) {
            int col = n0 + tn * 4 + j;
            float sc = gam[col] * rsqrtf(var[col] + BN_EPS);
            float v = (acc[i][j] + bias[col] - mu[col]) * sc + bet[col];
            out[(size_t)row * Nn + col] = fmaxf(v, 0.f);
        }
    }
}

__global__ __launch_bounds__(256)
void fc3_kernel(const float* __restrict__ A, const float* __restrict__ Bw,
                const float* __restrict__ bias, float* __restrict__ out) {
    int i = blockIdx.x * blockDim.x + threadIdx.x;
    if (i >= 1024 * 10) return;
    int n = i / 10, j = i % 10;
    const float4* a = (const float4*)&A[(size_t)n * 128];
    const float4* b = (const float4*)&Bw[(size_t)j * 128];
    float s = 0.f;
#pragma unroll
    for (int k = 0; k < 32; ++k) {
        float4 x = a[k], y = b[k];
        s += x.x * y.x + x.y * y.y + x.z * y.z + x.w * y.w;
    }
    out[i] = s + bias[j];
}

extern "C" void kernel_launch(void* const* d_in, const int* in_sizes, int n_in,
                              void* d_out, int out_size, void* d_ws, size_t ws_size,
                              hipStream_t stream) {
    (void)in_sizes; (void)n_in; (void)out_size; (void)ws_size;
    const float* x   = (const float*)d_in[0];
    const float* w1  = (const float*)d_in[1];
    const float* w2  = (const float*)d_in[2];
    const float* w3  = (const float*)d_in[3];
    const float* w4  = (const float*)d_in[4];
    const float* wf1 = (const float*)d_in[5];
    const float* wf2 = (const float*)d_in[6];
    const float* wf3 = (const float*)d_in[7];
    auto P = [&](int i) { return (const float*)d_in[i]; };
    char* wsb = (char*)d_ws;
    float* sums = (float*)(wsb + O_SUMS);
    float* w1r  = (float*)(wsb + O_W1R);
    float* wf2q = (float*)(wsb + O_WF2Q);
    float* wf3q = (float*)(wsb + O_WF3Q);
    u16* bq2   = (u16*)(wsb + O_BQ2);
    u16* bq3p  = (u16*)(wsb + O_BQ3);
    u16* bq4p  = (u16*)(wsb + O_BQ4);
    u16* bqf1  = (u16*)(wsb + O_BQF1);
    float* f1  = (float*)(wsb + O_F1);
    float* f2  = (float*)(wsb + O_F2);
    u16* act1  = (u16*)(wsb + O_ACT1);
    u16* act2p = (u16*)(wsb + O_ACT2);
    u16* act4p = (u16*)(wsb + O_ACT4);

    // ternarization: 3 launches
    zero_sums<<<1, 64, 0, stream>>>(sums);
    absmean_all<<<226, 256, 0, stream>>>(w1, w2, w3, w4, wf1, wf2, wf3, sums);
    tern_all<<<634, 256, 0, stream>>>(w1, w2, w3, w4, wf1, wf2, wf3, sums,
                                      w1r, bq2, bq3p, bq4p, bqf1, wf2q, wf3q);

    // border zeros + f1 zero (independent)
    border_zero<32, 30, 28><<<(1024 * 116 * 4 + 255) / 256, 256, 0, stream>>>(act1);
    border_zero<64, 16, 14><<<(1024 * 60 * 8 + 255) / 256, 256, 0, stream>>>(act2p);
    zero_f1<<<256, 256, 0, stream>>>(f1);

    // conv1 -> act1 (pad30 interior)
    conv1_direct<<<1024, 256, 0, stream>>>(x, w1r, P(8), P(9), P(10), P(11), P(12), act1);
    // conv2 + fused pool -> act2p (pad16 C=64 interior)
    convgemm<32, 64, 28, 30, 1, true, true><<<6272, 256, 0, stream>>>(
        act1, bq2, P(13), P(14), P(15), P(16), P(17), act2p);
    // fused conv3+conv4+pool -> act4p [1024*49][128]
    conv34<<<1024, 256, 0, stream>>>(
        act2p, bq3p, bq4p,
        P(18), P(19), P(20), P(21), P(22),
        P(23), P(24), P(25), P(26), P(27), act4p);
    // fc1 split-K (7 chunks of 896) -> atomic f32 into f1
    fc1gemm<<<dim3(8, 2, 7), 256, 0, stream>>>(act4p, bqf1, f1);
    // fc2 (applies fc1 BN+ReLU on A-load) -> f2
    fc2_kernel<<<dim3(2, 16), 256, 0, stream>>>(
        f1, wf2q, P(28), P(29), P(30), P(31), P(32),
        P(33), P(34), P(35), P(36), P(37), f2);
    // fc3 -> logits
    fc3_kernel<<<40, 256, 0, stream>>>(f2, wf3q, P(38), (float*)d_out);
}

// Round 11
// 418.478 us; speedup vs baseline: 1.7078x; 1.0343x over previous
//
#include <hip/hip_runtime.h>
#include <hip/hip_bf16.h>

#define BN_EPS 1e-5f

typedef __attribute__((ext_vector_type(8))) short bf16x8;
typedef __attribute__((ext_vector_type(4))) float f32x4;
typedef unsigned short u16;
typedef unsigned int u32;

__device__ __forceinline__ void load16(const void* g, void* l) {
    __builtin_amdgcn_global_load_lds((const __attribute__((address_space(1))) void*)g,
                                     (__attribute__((address_space(3))) void*)l, 16, 0, 0);
}
__device__ __forceinline__ u16 f2b(float v) {
    __hip_bfloat16 h = __float2bfloat16(v);
    return *reinterpret_cast<u16*>(&h);
}
__device__ __forceinline__ float ternq(float x, float d) {
    return (fabsf(x) > d) ? (x > 0.f ? 1.f : -1.f) : 0.f;
}

// ---------------- ws layout (BYTE offsets) ----------------
constexpr size_t ALGN(size_t x) { return (x + 255) & ~(size_t)255; }
constexpr size_t O_SUMS = 0;                                   // 8 f32
constexpr size_t O_W1R  = 256;                                 // 288 f32
constexpr size_t O_WF2Q = ALGN(O_W1R + 288 * 4);               // 32768 f32
constexpr size_t O_WF3Q = ALGN(O_WF2Q + 32768 * 4);            // 1280 f32
constexpr size_t O_BQ2  = ALGN(O_WF3Q + 1280 * 4);             // [64][288] bf16 (frag layout)
constexpr size_t O_BQ3  = ALGN(O_BQ2 + 64 * 288 * 2);          // B3' primed [18][8][64][8] bf16
constexpr size_t O_BQ4  = ALGN(O_BQ3 + 128 * 576 * 2);         // B4' primed [36][8][64][8] bf16
constexpr size_t O_BQF1 = ALGN(O_BQ4 + 128 * 1152 * 2);        // [256][6272] bf16
constexpr size_t O_F1   = ALGN(O_BQF1 + (size_t)256 * 6272 * 2);  // [1024][256] f32
constexpr size_t O_F2   = ALGN(O_F1 + 1024 * 256 * 4);         // [1024][128] f32
constexpr size_t O_ACT1 = ALGN(O_F2 + 1024 * 128 * 4);         // pad30 C=32 bf16
constexpr size_t O_ACT2 = ALGN(O_ACT1 + (size_t)1024 * 900 * 32 * 2);  // pad16 C=64
constexpr size_t O_ACT3 = ALGN(O_ACT2 + (size_t)1024 * 256 * 64 * 2);  // (unused)
constexpr size_t O_ACT4 = ALGN(O_ACT3 + (size_t)1024 * 256 * 128 * 2); // [1024*49][128]

// ---------------- ternarization (merged) ----------------
__global__ void zero_sums(float* s) { if (threadIdx.x < 8) s[threadIdx.x] = 0.f; }

__device__ void absmean_seg(const float* __restrict__ w, int n4, float* __restrict__ sum,
                            int b0, int nb) {
    __shared__ float sm[256];
    float s = 0.f;
    for (int i = b0 * 256 + threadIdx.x; i < n4; i += nb * 256) {
        float4 v = ((const float4*)w)[i];
        s += fabsf(v.x) + fabsf(v.y) + fabsf(v.z) + fabsf(v.w);
    }
    sm[threadIdx.x] = s;
    __syncthreads();
    for (int o = 128; o > 0; o >>= 1) {
        if (threadIdx.x < o) sm[threadIdx.x] += sm[threadIdx.x + o];
        __syncthreads();
    }
    if (threadIdx.x == 0) atomicAdd(sum, sm[0]);
}

__global__ void absmean_all(const float* w1, const float* w2, const float* w3, const float* w4,
                            const float* wf1, const float* wf2, const float* wf3, float* sums) {
    int b = blockIdx.x;
    if (b < 160)      absmean_seg(wf1, 401408, sums + 4, b, 160);
    else if (b < 192) absmean_seg(w4, 36864, sums + 3, b - 160, 32);
    else if (b < 208) absmean_seg(w3, 18432, sums + 2, b - 192, 16);
    else if (b < 216) absmean_seg(w2, 4608, sums + 1, b - 208, 8);
    else if (b < 224) absmean_seg(wf2, 8192, sums + 5, b - 216, 8);
    else if (b < 225) absmean_seg(w1, 72, sums + 0, 0, 1);
    else              absmean_seg(wf3, 320, sums + 6, 0, 1);
}

// conv2 weights: src [co][ci][9] -> frag layout [co][tap*CIN+ci]
__device__ void tern_conv_seg(const float* __restrict__ w, float d, u16* __restrict__ bq,
                              int COUT, int CIN, int b0, int nb) {
    int N = COUT * CIN * 9;
    for (int i = b0 * 256 + threadIdx.x; i < N; i += nb * 256) {
        float q = ternq(w[i], d);
        int co = i / (CIN * 9), r = i % (CIN * 9);
        int ci = r / 9, tap = r % 9;
        bq[(size_t)co * CIN * 9 + tap * CIN + ci] = f2b(q);
    }
}
// conv3/4 weights -> primed coalesced layout [s][nt][lane][8] (COUT=128)
__device__ void tern_conv_prime_seg(const float* __restrict__ w, float d, u16* __restrict__ bqp,
                                    int CIN, int b0, int nb) {
    int N = 128 * CIN * 9;
    for (int i = b0 * 256 + threadIdx.x; i < N; i += nb * 256) {
        float q = ternq(w[i], d);
        int co = i / (CIN * 9), r = i % (CIN * 9);
        int ci = r / 9, tap = r % 9;
        int k = tap * CIN + ci;
        int s = k >> 5, qd = (k & 31) >> 3, e = k & 7;
        int lane = qd * 16 + (co & 15), nt = co >> 4;
        bqp[((size_t)(s * 8 + nt) * 64 + lane) * 8 + e] = f2b(q);
    }
}
__device__ void tern_f32_seg(const float* __restrict__ w, float d, float* __restrict__ wq,
                             int N, int b0, int nb) {
    for (int i = b0 * 256 + threadIdx.x; i < N; i += nb * 256) wq[i] = ternq(w[i], d);
}

__global__ void tern_all(const float* w1, const float* w2, const float* w3, const float* w4,
                         const float* wf1, const float* wf2, const float* wf3,
                         const float* __restrict__ sums,
                         float* w1r, u16* bq2, u16* bq3p, u16* bq4p, u16* bqf1,
                         float* wf2q, float* wf3q) {
    int b = blockIdx.x;
    if (b < 1) {
        tern_f32_seg(w1, 0.7f * sums[0] / 288.f, w1r, 288, 0, 1);
    } else if (b < 9) {
        tern_conv_seg(w2, 0.7f * sums[1] / 18432.f, bq2, 64, 32, b - 1, 8);
    } else if (b < 41) {
        tern_conv_prime_seg(w3, 0.7f * sums[2] / 73728.f, bq3p, 64, b - 9, 32);
    } else if (b < 105) {
        tern_conv_prime_seg(w4, 0.7f * sums[3] / 147456.f, bq4p, 128, b - 41, 64);
    } else if (b < 617) {
        // wf1 [256][6272], k=c*49+s -> bf16 [256][s*128+c]
        float d = 0.7f * sums[4] / 1605632.f;
        for (int i = (b - 105) * 256 + threadIdx.x; i < 1605632; i += 512 * 256) {
            float q = ternq(wf1[i], d);
            int j = i / 6272, k = i % 6272;
            int c = k / 49, s = k % 49;
            bqf1[(size_t)j * 6272 + s * 128 + c] = f2b(q);
        }
    } else if (b < 633) {
        tern_f32_seg(wf2, 0.7f * sums[5] / 32768.f, wf2q, 32768, b - 617, 16);
    } else {
        tern_f32_seg(wf3, 0.7f * sums[6] / 1280.f, wf3q, 1280, 0, 1);
    }
}

__global__ void zero_f1(float* f1) {
    ((float4*)f1)[blockIdx.x * 256 + threadIdx.x] = make_float4(0.f, 0.f, 0.f, 0.f);
}

// ---------------- conv1 direct (Cin=1) -> pad30 NHWC bf16 ----------------
__global__ __launch_bounds__(256)
void conv1_direct(const float* __restrict__ x, const float* __restrict__ w1r,
                  const float* __restrict__ bias, const float* __restrict__ gam,
                  const float* __restrict__ bet, const float* __restrict__ mu,
                  const float* __restrict__ var, u16* __restrict__ out) {
    __shared__ float xs[784];
    __shared__ float wsh[288];
    __shared__ float scl[32], sft[32];
    const int n = blockIdx.x, tid = threadIdx.x;
    for (int i = tid; i < 784; i += 256) xs[i] = x[(size_t)n * 784 + i];
    for (int i = tid; i < 288; i += 256) wsh[i] = w1r[i];
    if (tid < 32) {
        float s = gam[tid] * rsqrtf(var[tid] + BN_EPS);
        scl[tid] = s;
        sft[tid] = (bias[tid] - mu[tid]) * s + bet[tid];
    }
    __syncthreads();
    for (int p = tid; p < 784; p += 256) {
        int y = p / 28, xx = p % 28;
        float patch[9];
#pragma unroll
        for (int dy = 0; dy < 3; ++dy)
#pragma unroll
            for (int dx = 0; dx < 3; ++dx) {
                int gy = y + dy - 1, gx = xx + dx - 1;
                patch[dy * 3 + dx] = (gy >= 0 && gy < 28 && gx >= 0 && gx < 28) ? xs[gy * 28 + gx] : 0.f;
            }
        u32 pk[16];
#pragma unroll
        for (int co = 0; co < 32; co += 2) {
            float s0 = 0.f, s1 = 0.f;
#pragma unroll
            for (int t = 0; t < 9; ++t) {
                s0 += wsh[co * 9 + t] * patch[t];
                s1 += wsh[(co + 1) * 9 + t] * patch[t];
            }
            float v0 = fmaxf(s0 * scl[co] + sft[co], 0.f);
            float v1 = fmaxf(s1 * scl[co + 1] + sft[co + 1], 0.f);
            pk[co >> 1] = ((u32)f2b(v1) << 16) | (u32)f2b(v0);
        }
        size_t base = ((size_t)(n * 30 + y + 1) * 30 + (xx + 1)) * 32;
#pragma unroll
        for (int q = 0; q < 4; ++q) ((uint4*)(out + base))[q] = ((uint4*)pk)[q];
    }
}

// ---------------- border zero for padded NHWC buffers ----------------
template<int C, int HP, int HV>
__global__ void border_zero(u16* __restrict__ buf) {
    constexpr int NB = 2 * HP + 2 * HV;
    constexpr int CG = C / 8;
    int i = blockIdx.x * blockDim.x + threadIdx.x;
    if (i >= 1024 * NB * CG) return;
    int cg = i % CG, r = i / CG;
    int b = r % NB, n = r / NB;
    int py, px;
    if (b < HP)               { py = 0;                  px = b; }
    else if (b < 2 * HP)      { py = HP - 1;             px = b - HP; }
    else if (b < 2 * HP + HV) { py = b - 2 * HP + 1;     px = 0; }
    else                      { py = b - 2 * HP - HV + 1; px = HP - 1; }
    size_t off = ((size_t)(n * HP + py) * HP + px) * C + cg * 8;
    *(uint4*)(buf + off) = make_uint4(0, 0, 0, 0);
}

// ---------------- conv2: R3-style implicit GEMM, frag-major LDS, fused pool ----------------
template<int CIN, int BN, int HV, int HP, int G, bool POOL, bool PADOUT>
__global__ __launch_bounds__(256)
void convgemm(const u16* __restrict__ act, const u16* __restrict__ bq,
              const float* __restrict__ bias, const float* __restrict__ gam,
              const float* __restrict__ bet, const float* __restrict__ mu,
              const float* __restrict__ var, u16* __restrict__ out) {
    constexpr int BM = 128;
    constexpr int K = 9 * CIN;
    constexpr int S = K / (32 * G);
    constexpr int TPC = CIN / 32;
    constexpr int NT = BN / 32;
    constexpr int RB = BN / 64;
    constexpr int HO = HV / 2;
    constexpr int PP = POOL ? HO * HO : HV * HV;

    __shared__ __align__(16) u16 Alds[G][BM * 32];
    __shared__ __align__(16) u16 Blds[G][BN * 32];
    __shared__ int rowA[BM];
    __shared__ int rowO[BM];
    __shared__ float scl[BN], sft[BN];

    const int tid = threadIdx.x;
    const int m0 = blockIdx.x * BM;

    for (int t = tid; t < BM; t += 256) {
        int base;
        if (POOL) {
            int p = (m0 >> 2) + (t >> 2), q = t & 3;
            int n = p / PP, rr = p % PP;
            int oy = rr / HO, ox = rr % HO;
            int y = oy * 2 + (q >> 1), x = ox * 2 + (q & 1);
            base = ((n * HP + y) * HP + x) * CIN;
        } else {
            int m = m0 + t;
            int n = m / PP, rr = m % PP;
            int y = rr / HV, x = rr % HV;
            base = ((n * HP + y) * HP + x) * CIN;
        }
        rowA[t] = base;
    }
    if (POOL) {
        if (tid < 32) {
            int p = (m0 >> 2) + tid;
            int n = p / PP, rr = p % PP;
            int oy = rr / HO, ox = rr % HO;
            rowO[tid] = PADOUT ? ((n * 16 + oy + 1) * 16 + ox + 1) * BN : p * BN;
        }
    } else {
        for (int t = tid; t < BM; t += 256) {
            int m = m0 + t;
            int n = m / PP, rr = m % PP;
            int y = rr / HV, x = rr % HV;
            rowO[t] = PADOUT ? ((n * 16 + y + 1) * 16 + x + 1) * BN : m * BN;
        }
    }
    if (tid < BN) {
        float s = gam[tid] * rsqrtf(var[tid] + BN_EPS);
        scl[tid] = s;
        sft[tid] = (bias[tid] - mu[tid]) * s + bet[tid];
    }
    __syncthreads();

    int arow[2];
    arow[0] = rowA[(tid >> 6) * 16 + (tid & 15)];
    arow[1] = rowA[64 + (tid >> 6) * 16 + (tid & 15)];
    const int chunkb = ((tid >> 4) & 3) * 16;
    const int bco = (tid >> 6) * 16 + (tid & 15);
    const char* actb = (const char*)act;
    const char* bqb  = (const char*)bq;

    const int wave = tid >> 6, lane = tid & 63;
    const int wm = wave & 1, wn = wave >> 1;
    const int fr16 = lane * 16;

    f32x4 acc[4][NT] = {};

    for (int s = 0; s < S; ++s) {
#pragma unroll
        for (int j = 0; j < G; ++j) {
            int g = s * G + j;
            int tap = g / TPC, cio = (g % TPC) * 32;
            int dy = tap / 3, dx = tap % 3;
            int toffb = ((dy * HP + dx) * CIN + cio) * 2;
            char* Al = (char*)Alds[j];
#pragma unroll
            for (int r = 0; r < 2; ++r)
                load16(actb + (size_t)arow[r] * 2 + toffb + chunkb, Al + r * 4096 + tid * 16);
            char* Bl = (char*)Blds[j];
            int bkob = g * 64 + chunkb;
#pragma unroll
            for (int r = 0; r < RB; ++r)
                load16(bqb + (size_t)(r * 64 + bco) * K * 2 + bkob, Bl + r * 4096 + tid * 16);
        }
        __syncthreads();
#pragma unroll
        for (int j = 0; j < G; ++j) {
            const char* Al = (const char*)Alds[j];
            const char* Bl = (const char*)Blds[j];
            bf16x8 af[4], bf[NT];
#pragma unroll
            for (int mt = 0; mt < 4; ++mt)
                af[mt] = *(const bf16x8*)(Al + (wm * 4 + mt) * 1024 + fr16);
#pragma unroll
            for (int nt = 0; nt < NT; ++nt)
                bf[nt] = *(const bf16x8*)(Bl + (wn * NT + nt) * 1024 + fr16);
#pragma unroll
            for (int mt = 0; mt < 4; ++mt)
#pragma unroll
                for (int nt = 0; nt < NT; ++nt)
                    acc[mt][nt] = __builtin_amdgcn_mfma_f32_16x16x32_bf16(af[mt], bf[nt], acc[mt][nt], 0, 0, 0);
        }
        __syncthreads();
    }

    const int fr = lane & 15, quad = lane >> 4;
    if (POOL) {
#pragma unroll
        for (int mt = 0; mt < 4; ++mt) {
            int pl = wm * 16 + mt * 4 + quad;
            int ob = rowO[pl];
#pragma unroll
            for (int nt = 0; nt < NT; ++nt) {
                int col = wn * (NT * 16) + nt * 16 + fr;
                float sc = scl[col], sh = sft[col];
                f32x4 a = acc[mt][nt];
                float v0 = a[0] * sc + sh, v1 = a[1] * sc + sh;
                float v2 = a[2] * sc + sh, v3 = a[3] * sc + sh;
                float mx = fmaxf(fmaxf(v0, v1), fmaxf(v2, v3));
                out[(size_t)ob + col] = f2b(fmaxf(mx, 0.f));
            }
        }
    } else {
#pragma unroll
        for (int mt = 0; mt < 4; ++mt) {
            int rb = wm * 64 + mt * 16 + quad * 4;
            int o0 = rowO[rb], o1 = rowO[rb + 1], o2 = rowO[rb + 2], o3 = rowO[rb + 3];
#pragma unroll
            for (int nt = 0; nt < NT; ++nt) {
                int col = wn * (NT * 16) + nt * 16 + fr;
                float sc = scl[col], sh = sft[col];
                f32x4 a = acc[mt][nt];
                out[(size_t)o0 + col] = f2b(fmaxf(a[0] * sc + sh, 0.f));
                out[(size_t)o1 + col] = f2b(fmaxf(a[1] * sc + sh, 0.f));
                out[(size_t)o2 + col] = f2b(fmaxf(a[2] * sc + sh, 0.f));
                out[(size_t)o3 + col] = f2b(fmaxf(a[3] * sc + sh, 0.f));
            }
        }
    }
}

// ---------------- conv34 v5: per-image fused conv3+conv4+pool ----------------
// 2x2 wave grid (wm x wn): A-dup 2, B-dup 2 (B vmem traffic halved vs row-split).
// mt=7 valid-y tiles (y = wm*7+mtl+1; 224 rows, no y-junk MFMA). Padded-stride
// LDS addressing (X2 144B, X3/X4 272B; loop-invariant base + per-tap scalar add).
// Arena rows -1..256 (258 x 272 = 70176B -> 2 blocks/CU). Junk x outputs feed
// nothing stored; garbage edge rows feed only junk x. unroll-1 taps (no spill).
__global__ __launch_bounds__(256)
void conv34(const u16* __restrict__ act2p, const u16* __restrict__ b3p, const u16* __restrict__ b4p,
            const float* __restrict__ b3, const float* __restrict__ g3, const float* __restrict__ be3,
            const float* __restrict__ m3, const float* __restrict__ v3,
            const float* __restrict__ b4, const float* __restrict__ g4, const float* __restrict__ be4,
            const float* __restrict__ m4, const float* __restrict__ v4,
            u16* __restrict__ out) {
    __shared__ __align__(16) char X[258 * 272];   // 70176 B; X2 uses 258*144

    const int tid = threadIdx.x;
    const int n = blockIdx.x;
    const int wave = tid >> 6, lane = tid & 63;
    const int wm = wave & 1, wn = wave >> 1;
    const int fr = lane & 15, quad = lane >> 4;

    // phase A: stage X2 rows 0..255 at physical (r+1), stride 144B
    {
        const uint4* src = (const uint4*)(act2p + (size_t)n * 16384);
#pragma unroll
        for (int it = 0; it < 8; ++it) {
            int i = it * 256 + tid;
            int r = i >> 3, c = i & 7;
            *(uint4*)(X + (r + 1) * 144 + c * 16) = src[i];
        }
    }
    __syncthreads();

    f32x4 acc[7][4] = {};

    // phase B: conv3, K=576 (9 taps x 2 halves), barrier-free
    {
        const char* B3 = (const char*)b3p;
        int ab[7];
#pragma unroll
        for (int mtl = 0; mtl < 7; ++mtl)
            ab[mtl] = ((wm * 7 + mtl + 1) * 16 + fr) * 144 + quad * 16;
#pragma unroll 1
        for (int tap = 0; tap < 9; ++tap) {
            const int ib = ((tap / 3) * 16 + (tap % 3) - 16) * 144;   // (+1 phys, -17 off)
#pragma unroll
            for (int h = 0; h < 2; ++h) {
                const int s = tap * 2 + h;
                bf16x8 af[7], bf[4];
#pragma unroll
                for (int mtl = 0; mtl < 7; ++mtl)
                    af[mtl] = *(const bf16x8*)(X + ab[mtl] + ib + h * 64);
#pragma unroll
                for (int nt = 0; nt < 4; ++nt)
                    bf[nt] = *(const bf16x8*)(B3 + (size_t)((s * 8 + wn * 4 + nt) * 64 + lane) * 16);
#pragma unroll
                for (int mtl = 0; mtl < 7; ++mtl)
#pragma unroll
                    for (int nt = 0; nt < 4; ++nt)
                        acc[mtl][nt] = __builtin_amdgcn_mfma_f32_16x16x32_bf16(af[mtl], bf[nt], acc[mtl][nt], 0, 0, 0);
            }
        }
    }
    __syncthreads();   // all X2 reads done; X3 may overwrite

    // phase C: build X3 (stride 272B, physical row = m+1, cols linear); borders zero
    {
        float scl3[4], sft3[4];
#pragma unroll
        for (int nt = 0; nt < 4; ++nt) {
            int c = wn * 64 + nt * 16 + fr;
            float s = g3[c] * rsqrtf(v3[c] + BN_EPS);
            scl3[nt] = s;
            sft3[nt] = (b3[c] - m3[c]) * s + be3[c];
        }
        for (int t = tid; t < 960; t += 256) {
            int ch = t & 15, b = t >> 4;
            int m = (b < 16) ? b : (b < 32) ? 224 + b : (b < 46) ? (b - 31) * 16 : (b - 45) * 16 + 15;
            *(uint4*)(X + (m + 1) * 272 + ch * 16) = make_uint4(0, 0, 0, 0);
        }
#pragma unroll
        for (int mtl = 0; mtl < 7; ++mtl) {
            int y = wm * 7 + mtl + 1;
#pragma unroll
            for (int j = 0; j < 4; ++j) {
                int x = quad * 4 + j;
                if (x >= 1 && x <= 14) {
                    char* row = X + (y * 16 + x + 1) * 272;
#pragma unroll
                    for (int nt = 0; nt < 4; ++nt) {
                        int col = wn * 64 + nt * 16 + fr;
                        float v = fmaxf(acc[mtl][nt][j] * scl3[nt] + sft3[nt], 0.f);
                        *(u16*)(row + col * 2) = f2b(v);
                    }
                }
            }
        }
    }
    __syncthreads();

    // phase D: conv4, K=1152 (9 taps x 4 quarters), barrier-free
#pragma unroll
    for (int a = 0; a < 7; ++a)
#pragma unroll
        for (int b = 0; b < 4; ++b) acc[a][b] = (f32x4){0.f, 0.f, 0.f, 0.f};
    {
        const char* B4 = (const char*)b4p;
        int ab[7];
#pragma unroll
        for (int mtl = 0; mtl < 7; ++mtl)
            ab[mtl] = ((wm * 7 + mtl + 1) * 16 + fr) * 272 + quad * 16;
#pragma unroll 1
        for (int tap = 0; tap < 9; ++tap) {
            const int ib = ((tap / 3) * 16 + (tap % 3) - 16) * 272;
#pragma unroll
            for (int qr = 0; qr < 4; ++qr) {
                const int s = tap * 4 + qr;
                bf16x8 af[7], bf[4];
#pragma unroll
                for (int mtl = 0; mtl < 7; ++mtl)
                    af[mtl] = *(const bf16x8*)(X + ab[mtl] + ib + qr * 64);
#pragma unroll
                for (int nt = 0; nt < 4; ++nt)
                    bf[nt] = *(const bf16x8*)(B4 + (size_t)((s * 8 + wn * 4 + nt) * 64 + lane) * 16);
#pragma unroll
                for (int mtl = 0; mtl < 7; ++mtl)
#pragma unroll
                    for (int nt = 0; nt < 4; ++nt)
                        acc[mtl][nt] = __builtin_amdgcn_mfma_f32_16x16x32_bf16(af[mtl], bf[nt], acc[mtl][nt], 0, 0, 0);
            }
        }
    }
    __syncthreads();   // X3 reads done; reuse as X4

    // phase E: write post-BN-ReLU conv4 rows y in 1..14 (junk x written, never pooled)
    {
        float scl4[4], sft4[4];
#pragma unroll
        for (int nt = 0; nt < 4; ++nt) {
            int c = wn * 64 + nt * 16 + fr;
            float s = g4[c] * rsqrtf(v4[c] + BN_EPS);
            scl4[nt] = s;
            sft4[nt] = (b4[c] - m4[c]) * s + be4[c];
        }
#pragma unroll
        for (int mtl = 0; mtl < 7; ++mtl) {
            int y = wm * 7 + mtl + 1;
#pragma unroll
            for (int j = 0; j < 4; ++j) {
                char* row = X + (y * 16 + quad * 4 + j + 1) * 272;
#pragma unroll
                for (int nt = 0; nt < 4; ++nt) {
                    int col = wn * 64 + nt * 16 + fr;
                    float v = fmaxf(acc[mtl][nt][j] * scl4[nt] + sft4[nt], 0.f);
                    *(u16*)(row + col * 2) = f2b(v);
                }
            }
        }
    }
    __syncthreads();

    // pool phase: 49 px x 16 chunks; bf16 >= 0 so u16 compare == float compare
    for (int t = tid; t < 784; t += 256) {
        int ch = t & 15, p = t >> 4;
        int oy = p / 7, ox = p % 7;
        int r00 = (2 * oy + 1) * 16 + (2 * ox + 1) + 1;
        uint4 A0 = *(const uint4*)(X + (r00) * 272 + ch * 16);
        uint4 A1 = *(const uint4*)(X + (r00 + 1) * 272 + ch * 16);
        uint4 A2 = *(const uint4*)(X + (r00 + 16) * 272 + ch * 16);
        uint4 A3 = *(const uint4*)(X + (r00 + 17) * 272 + ch * 16);
        const u16* pa = (const u16*)&A0;
        const u16* pb = (const u16*)&A1;
        const u16* pc = (const u16*)&A2;
        const u16* pd = (const u16*)&A3;
        u16 o[8];
#pragma unroll
        for (int e = 0; e < 8; ++e)
            o[e] = (u16)max(max((int)pa[e], (int)pb[e]), max((int)pc[e], (int)pd[e]));
        *(uint4*)(out + ((size_t)n * 49 + p) * 128 + ch * 8) = *(const uint4*)o;
    }
}

// ---------------- fc1: split-K MFMA GEMM (LDS dbuf), atomicAdd f32 into f1 ----------------
__global__ __launch_bounds__(256)
void fc1gemm(const u16* __restrict__ A, const u16* __restrict__ Bq, float* __restrict__ out) {
    constexpr int K = 6272, KC = 896, S = KC / 64;
    __shared__ __align__(16) u16 Alds[2][128 * 32];
    __shared__ __align__(16) u16 Blds[2][128 * 32];
    const int tid = threadIdx.x;
    const int m0 = blockIdx.x * 128;
    const int n0 = blockIdx.y * 128;
    const int k0 = blockIdx.z * KC;
    const int chunkb = ((tid >> 4) & 3) * 16;
    const int rr = (tid >> 6) * 16 + (tid & 15);
    const char* Ag = (const char*)A;
    const char* Bg = (const char*)Bq;
    const int wave = tid >> 6, lane = tid & 63;
    const int wm = wave & 1, wn = wave >> 1;
    const int fr16 = lane * 16;
    f32x4 acc[4][4] = {};

    for (int s = 0; s < S; ++s) {
#pragma unroll
        for (int j = 0; j < 2; ++j) {
            int kb = (k0 + s * 64 + j * 32) * 2 + chunkb;
            char* Al = (char*)Alds[j];
            char* Bl = (char*)Blds[j];
#pragma unroll
            for (int r = 0; r < 2; ++r) {
                load16(Ag + (size_t)(m0 + r * 64 + rr) * K * 2 + kb, Al + r * 4096 + tid * 16);
                load16(Bg + (size_t)(n0 + r * 64 + rr) * K * 2 + kb, Bl + r * 4096 + tid * 16);
            }
        }
        __syncthreads();
#pragma unroll
        for (int j = 0; j < 2; ++j) {
            const char* Al = (const char*)Alds[j];
            const char* Bl = (const char*)Blds[j];
            bf16x8 af[4], bf[4];
#pragma unroll
            for (int mt = 0; mt < 4; ++mt)
                af[mt] = *(const bf16x8*)(Al + (wm * 4 + mt) * 1024 + fr16);
#pragma unroll
            for (int nt = 0; nt < 4; ++nt)
                bf[nt] = *(const bf16x8*)(Bl + (wn * 4 + nt) * 1024 + fr16);
#pragma unroll
            for (int mt = 0; mt < 4; ++mt)
#pragma unroll
                for (int nt = 0; nt < 4; ++nt)
                    acc[mt][nt] = __builtin_amdgcn_mfma_f32_16x16x32_bf16(af[mt], bf[nt], acc[mt][nt], 0, 0, 0);
        }
        __syncthreads();
    }
    const int fr = lane & 15, quad = lane >> 4;
#pragma unroll
    for (int mt = 0; mt < 4; ++mt) {
        int row = m0 + wm * 64 + mt * 16 + quad * 4;
#pragma unroll
        for (int nt = 0; nt < 4; ++nt) {
            int col = n0 + wn * 64 + nt * 16 + fr;
            f32x4 a = acc[mt][nt];
            atomicAdd(&out[(size_t)(row + 0) * 256 + col], a[0]);
            atomicAdd(&out[(size_t)(row + 1) * 256 + col], a[1]);
            atomicAdd(&out[(size_t)(row + 2) * 256 + col], a[2]);
            atomicAdd(&out[(size_t)(row + 3) * 256 + col], a[3]);
        }
    }
}

// ---------------- fc2 fp32 GEMM; applies fc1's BN+ReLU to A on load ----------------
__global__ __launch_bounds__(256)
void fc2_kernel(const float* __restrict__ A, const float* __restrict__ Bw,
                const float* __restrict__ bA, const float* __restrict__ gA,
                const float* __restrict__ beA, const float* __restrict__ mA,
                const float* __restrict__ vA,
                const float* __restrict__ bias, const float* __restrict__ gam,
                const float* __restrict__ bet, const float* __restrict__ mu,
                const float* __restrict__ var, float* __restrict__ out) {
    constexpr int Nn = 128, K = 256;
    __shared__ __align__(16) float As[16][68];
    __shared__ __align__(16) float Bs[16][68];
    __shared__ float sclA[256], sftA[256];
    const int tid = threadIdx.x;
    const int n0 = blockIdx.x * 64, m0 = blockIdx.y * 64;
    if (tid < 256) {
        float s = gA[tid] * rsqrtf(vA[tid] + BN_EPS);
        sclA[tid] = s;
        sftA[tid] = (bA[tid] - mA[tid]) * s + beA[tid];
    }
    const int tm = tid >> 4, tn = tid & 15;
    const int lr = tid >> 2, lk = (tid & 3) * 4;
    float acc[4][4] = {};
    __syncthreads();
    for (int k0 = 0; k0 < K; k0 += 16) {
        float4 av = *(const float4*)&A[(size_t)(m0 + lr) * K + k0 + lk];
        float4 bv = *(const float4*)&Bw[(size_t)(n0 + lr) * K + k0 + lk];
        As[lk + 0][lr] = fmaxf(av.x * sclA[k0 + lk + 0] + sftA[k0 + lk + 0], 0.f);
        As[lk + 1][lr] = fmaxf(av.y * sclA[k0 + lk + 1] + sftA[k0 + lk + 1], 0.f);
        As[lk + 2][lr] = fmaxf(av.z * sclA[k0 + lk + 2] + sftA[k0 + lk + 2], 0.f);
        As[lk + 3][lr] = fmaxf(av.w * sclA[k0 + lk + 3] + sftA[k0 + lk + 3], 0.f);
        Bs[lk + 0][lr] = bv.x; Bs[lk + 1][lr] = bv.y; Bs[lk + 2][lr] = bv.z; Bs[lk + 3][lr] = bv.w;
        __syncthreads();
#pragma unroll
        for (int k = 0; k < 16; ++k) {
            float4 a = *(const float4*)&As[k][tm * 4];
            float4 b = *(const float4*)&Bs[k][tn * 4];
            acc[0][0] += a.x * b.x; acc[0][1] += a.x * b.y; acc[0][2] += a.x * b.z; acc[0][3] += a.x * b.w;
            acc[1][0] += a.y * b.x; acc[1][1] += a.y * b.y; acc[1][2] += a.y * b.z; acc[1][3] += a.y * b.w;
            acc[2][0] += a.z * b.x; acc[2][1] += a.z * b.y; acc[2][2] += a.z * b.z; acc[2][3] += a.z * b.w;
            acc[3][0] += a.w * b.x; acc[3][1] += a.w * b.y; acc[3][2] += a.w * b.z; acc[3][3] += a.w * b.w;
        }
        __syncthreads();
    }
#pragma unroll
    for (int i = 0; i < 4; ++i) {
        int row = m0 + tm * 4 + i;
#pragma unroll
        for (int j = 0; j < 4; ++j) {
            int col = n0 + tn * 4 + j;
            float sc = gam[col] * rsqrtf(var[col] + BN_EPS);
            float v = (acc[i][j] + bias[col] - mu[col]) * sc + bet[col];
            out[(size_t)row * Nn + col] = fmaxf(v, 0.f);
        }
    }
}

__global__ __launch_bounds__(256)
void fc3_kernel(const float* __restrict__ A, const float* __restrict__ Bw,
                const float* __restrict__ bias, float* __restrict__ out) {
    int i = blockIdx.x * blockDim.x + threadIdx.x;
    if (i >= 1024 * 10) return;
    int n = i / 10, j = i % 10;
    const float4* a = (const float4*)&A[(size_t)n * 128];
    const float4* b = (const float4*)&Bw[(size_t)j * 128];
    float s = 0.f;
#pragma unroll
    for (int k = 0; k < 32; ++k) {
        float4 x = a[k], y = b[k];
        s += x.x * y.x + x.y * y.y + x.z * y.z + x.w * y.w;
    }
    out[i] = s + bias[j];
}

extern "C" void kernel_launch(void* const* d_in, const int* in_sizes, int n_in,
                              void* d_out, int out_size, void* d_ws, size_t ws_size,
                              hipStream_t stream) {
    (void)in_sizes; (void)n_in; (void)out_size; (void)ws_size;
    const float* x   = (const float*)d_in[0];
    const float* w1  = (const float*)d_in[1];
    const float* w2  = (const float*)d_in[2];
    const float* w3  = (const float*)d_in[3];
    const float* w4  = (const float*)d_in[4];
    const float* wf1 = (const float*)d_in[5];
    const float* wf2 = (const float*)d_in[6];
    const float* wf3 = (const float*)d_in[7];
    auto P = [&](int i) { return (const float*)d_in[i]; };
    char* wsb = (char*)d_ws;
    float* sums = (float*)(wsb + O_SUMS);
    float* w1r  = (float*)(wsb + O_W1R);
    float* wf2q = (float*)(wsb + O_WF2Q);
    float* wf3q = (float*)(wsb + O_WF3Q);
    u16* bq2   = (u16*)(wsb + O_BQ2);
    u16* bq3p  = (u16*)(wsb + O_BQ3);
    u16* bq4p  = (u16*)(wsb + O_BQ4);
    u16* bqf1  = (u16*)(wsb + O_BQF1);
    float* f1  = (float*)(wsb + O_F1);
    float* f2  = (float*)(wsb + O_F2);
    u16* act1  = (u16*)(wsb + O_ACT1);
    u16* act2p = (u16*)(wsb + O_ACT2);
    u16* act4p = (u16*)(wsb + O_ACT4);

    // ternarization: 3 launches
    zero_sums<<<1, 64, 0, stream>>>(sums);
    absmean_all<<<226, 256, 0, stream>>>(w1, w2, w3, w4, wf1, wf2, wf3, sums);
    tern_all<<<634, 256, 0, stream>>>(w1, w2, w3, w4, wf1, wf2, wf3, sums,
                                      w1r, bq2, bq3p, bq4p, bqf1, wf2q, wf3q);

    // border zeros + f1 zero (independent)
    border_zero<32, 30, 28><<<(1024 * 116 * 4 + 255) / 256, 256, 0, stream>>>(act1);
    border_zero<64, 16, 14><<<(1024 * 60 * 8 + 255) / 256, 256, 0, stream>>>(act2p);
    zero_f1<<<256, 256, 0, stream>>>(f1);

    // conv1 -> act1 (pad30 interior)
    conv1_direct<<<1024, 256, 0, stream>>>(x, w1r, P(8), P(9), P(10), P(11), P(12), act1);
    // conv2 + fused pool -> act2p (pad16 C=64 interior)
    convgemm<32, 64, 28, 30, 1, true, true><<<6272, 256, 0, stream>>>(
        act1, bq2, P(13), P(14), P(15), P(16), P(17), act2p);
    // fused conv3+conv4+pool -> act4p [1024*49][128]
    conv34<<<1024, 256, 0, stream>>>(
        act2p, bq3p, bq4p,
        P(18), P(19), P(20), P(21), P(22),
        P(23), P(24), P(25), P(26), P(27), act4p);
    // fc1 split-K (7 chunks of 896) -> atomic f32 into f1
    fc1gemm<<<dim3(8, 2, 7), 256, 0, stream>>>(act4p, bqf1, f1);
    // fc2 (applies fc1 BN+ReLU on A-load) -> f2
    fc2_kernel<<<dim3(2, 16), 256, 0, stream>>>(
        f1, wf2q, P(28), P(29), P(30), P(31), P(32),
        P(33), P(34), P(35), P(36), P(37), f2);
    // fc3 -> logits
    fc3_kernel<<<40, 256, 0, stream>>>(f2, wf3q, P(38), (float*)d_out);
}

// Round 12
// 408.422 us; speedup vs baseline: 1.7498x; 1.0246x over previous
//
#include <hip/hip_runtime.h>
#include <hip/hip_bf16.h>

#define BN_EPS 1e-5f

typedef __attribute__((ext_vector_type(8))) short bf16x8;
typedef __attribute__((ext_vector_type(4))) float f32x4;
typedef unsigned short u16;
typedef unsigned int u32;

__device__ __forceinline__ void load16(const void* g, void* l) {
    __builtin_amdgcn_global_load_lds((const __attribute__((address_space(1))) void*)g,
                                     (__attribute__((address_space(3))) void*)l, 16, 0, 0);
}
__device__ __forceinline__ u16 f2b(float v) {
    __hip_bfloat16 h = __float2bfloat16(v);
    return *reinterpret_cast<u16*>(&h);
}
__device__ __forceinline__ float ternq(float x, float d) {
    return (fabsf(x) > d) ? (x > 0.f ? 1.f : -1.f) : 0.f;
}

// ---------------- ws layout (BYTE offsets) ----------------
constexpr size_t ALGN(size_t x) { return (x + 255) & ~(size_t)255; }
constexpr size_t O_SUMS = 0;                                   // 8 f32
constexpr size_t O_W1R  = 256;                                 // 288 f32
constexpr size_t O_WF2Q = ALGN(O_W1R + 288 * 4);               // 32768 f32
constexpr size_t O_WF3Q = ALGN(O_WF2Q + 32768 * 4);            // 1280 f32
constexpr size_t O_BQ2  = ALGN(O_WF3Q + 1280 * 4);             // [64][288] bf16 (frag layout)
constexpr size_t O_BQ3  = ALGN(O_BQ2 + 64 * 288 * 2);          // B3' primed [18][8][64][8] bf16
constexpr size_t O_BQ4  = ALGN(O_BQ3 + 128 * 576 * 2);         // B4' primed [36][8][64][8] bf16
constexpr size_t O_BQF1 = ALGN(O_BQ4 + 128 * 1152 * 2);        // [256][6272] bf16
constexpr size_t O_F1   = ALGN(O_BQF1 + (size_t)256 * 6272 * 2);  // [1024][256] f32
constexpr size_t O_F2   = ALGN(O_F1 + 1024 * 256 * 4);         // [1024][128] f32
constexpr size_t O_ACT1 = ALGN(O_F2 + 1024 * 128 * 4);         // pad30 C=32 bf16
constexpr size_t O_ACT2 = ALGN(O_ACT1 + (size_t)1024 * 900 * 32 * 2);  // pad16 C=64
constexpr size_t O_ACT3 = ALGN(O_ACT2 + (size_t)1024 * 256 * 64 * 2);  // (unused)
constexpr size_t O_ACT4 = ALGN(O_ACT3 + (size_t)1024 * 256 * 128 * 2); // [1024*49][128]

// ---------------- ternarization (merged) ----------------
__global__ void zero_sums(float* s) { if (threadIdx.x < 8) s[threadIdx.x] = 0.f; }

__device__ void absmean_seg(const float* __restrict__ w, int n4, float* __restrict__ sum,
                            int b0, int nb) {
    __shared__ float sm[256];
    float s = 0.f;
    for (int i = b0 * 256 + threadIdx.x; i < n4; i += nb * 256) {
        float4 v = ((const float4*)w)[i];
        s += fabsf(v.x) + fabsf(v.y) + fabsf(v.z) + fabsf(v.w);
    }
    sm[threadIdx.x] = s;
    __syncthreads();
    for (int o = 128; o > 0; o >>= 1) {
        if (threadIdx.x < o) sm[threadIdx.x] += sm[threadIdx.x + o];
        __syncthreads();
    }
    if (threadIdx.x == 0) atomicAdd(sum, sm[0]);
}

__global__ void absmean_all(const float* w1, const float* w2, const float* w3, const float* w4,
                            const float* wf1, const float* wf2, const float* wf3, float* sums) {
    int b = blockIdx.x;
    if (b < 160)      absmean_seg(wf1, 401408, sums + 4, b, 160);
    else if (b < 192) absmean_seg(w4, 36864, sums + 3, b - 160, 32);
    else if (b < 208) absmean_seg(w3, 18432, sums + 2, b - 192, 16);
    else if (b < 216) absmean_seg(w2, 4608, sums + 1, b - 208, 8);
    else if (b < 224) absmean_seg(wf2, 8192, sums + 5, b - 216, 8);
    else if (b < 225) absmean_seg(w1, 72, sums + 0, 0, 1);
    else              absmean_seg(wf3, 320, sums + 6, 0, 1);
}

// conv2 weights: src [co][ci][9] -> frag layout [co][tap*CIN+ci]
__device__ void tern_conv_seg(const float* __restrict__ w, float d, u16* __restrict__ bq,
                              int COUT, int CIN, int b0, int nb) {
    int N = COUT * CIN * 9;
    for (int i = b0 * 256 + threadIdx.x; i < N; i += nb * 256) {
        float q = ternq(w[i], d);
        int co = i / (CIN * 9), r = i % (CIN * 9);
        int ci = r / 9, tap = r % 9;
        bq[(size_t)co * CIN * 9 + tap * CIN + ci] = f2b(q);
    }
}
// conv3/4 weights -> primed coalesced layout [s][nt][lane][8] (COUT=128)
__device__ void tern_conv_prime_seg(const float* __restrict__ w, float d, u16* __restrict__ bqp,
                                    int CIN, int b0, int nb) {
    int N = 128 * CIN * 9;
    for (int i = b0 * 256 + threadIdx.x; i < N; i += nb * 256) {
        float q = ternq(w[i], d);
        int co = i / (CIN * 9), r = i % (CIN * 9);
        int ci = r / 9, tap = r % 9;
        int k = tap * CIN + ci;
        int s = k >> 5, qd = (k & 31) >> 3, e = k & 7;
        int lane = qd * 16 + (co & 15), nt = co >> 4;
        bqp[((size_t)(s * 8 + nt) * 64 + lane) * 8 + e] = f2b(q);
    }
}
__device__ void tern_f32_seg(const float* __restrict__ w, float d, float* __restrict__ wq,
                             int N, int b0, int nb) {
    for (int i = b0 * 256 + threadIdx.x; i < N; i += nb * 256) wq[i] = ternq(w[i], d);
}

__global__ void tern_all(const float* w1, const float* w2, const float* w3, const float* w4,
                         const float* wf1, const float* wf2, const float* wf3,
                         const float* __restrict__ sums,
                         float* w1r, u16* bq2, u16* bq3p, u16* bq4p, u16* bqf1,
                         float* wf2q, float* wf3q) {
    int b = blockIdx.x;
    if (b < 1) {
        tern_f32_seg(w1, 0.7f * sums[0] / 288.f, w1r, 288, 0, 1);
    } else if (b < 9) {
        tern_conv_seg(w2, 0.7f * sums[1] / 18432.f, bq2, 64, 32, b - 1, 8);
    } else if (b < 41) {
        tern_conv_prime_seg(w3, 0.7f * sums[2] / 73728.f, bq3p, 64, b - 9, 32);
    } else if (b < 105) {
        tern_conv_prime_seg(w4, 0.7f * sums[3] / 147456.f, bq4p, 128, b - 41, 64);
    } else if (b < 617) {
        // wf1 [256][6272], k=c*49+s -> bf16 [256][s*128+c]
        float d = 0.7f * sums[4] / 1605632.f;
        for (int i = (b - 105) * 256 + threadIdx.x; i < 1605632; i += 512 * 256) {
            float q = ternq(wf1[i], d);
            int j = i / 6272, k = i % 6272;
            int c = k / 49, s = k % 49;
            bqf1[(size_t)j * 6272 + s * 128 + c] = f2b(q);
        }
    } else if (b < 633) {
        tern_f32_seg(wf2, 0.7f * sums[5] / 32768.f, wf2q, 32768, b - 617, 16);
    } else {
        tern_f32_seg(wf3, 0.7f * sums[6] / 1280.f, wf3q, 1280, 0, 1);
    }
}

// ---------------- merged init: border zeros + f1 zero (one launch) ----------------
template<int C, int HP, int HV>
__device__ void border_zero_dev(u16* __restrict__ buf, int i) {
    constexpr int NB = 2 * HP + 2 * HV;
    constexpr int CG = C / 8;
    if (i >= 1024 * NB * CG) return;
    int cg = i % CG, r = i / CG;
    int b = r % NB, n = r / NB;
    int py, px;
    if (b < HP)               { py = 0;                  px = b; }
    else if (b < 2 * HP)      { py = HP - 1;             px = b - HP; }
    else if (b < 2 * HP + HV) { py = b - 2 * HP + 1;     px = 0; }
    else                      { py = b - 2 * HP - HV + 1; px = HP - 1; }
    size_t off = ((size_t)(n * HP + py) * HP + px) * C + cg * 8;
    *(uint4*)(buf + off) = make_uint4(0, 0, 0, 0);
}

__global__ void init_bufs(u16* __restrict__ act1, u16* __restrict__ act2p, float* __restrict__ f1) {
    int b = blockIdx.x, tid = threadIdx.x;
    if (b < 1856) {
        border_zero_dev<32, 30, 28>(act1, b * 256 + tid);
    } else if (b < 3776) {
        border_zero_dev<64, 16, 14>(act2p, (b - 1856) * 256 + tid);
    } else {
        ((float4*)f1)[(b - 3776) * 256 + tid] = make_float4(0.f, 0.f, 0.f, 0.f);
    }
}

// ---------------- conv1 direct (Cin=1) -> pad30 NHWC bf16 ----------------
__global__ __launch_bounds__(256)
void conv1_direct(const float* __restrict__ x, const float* __restrict__ w1r,
                  const float* __restrict__ bias, const float* __restrict__ gam,
                  const float* __restrict__ bet, const float* __restrict__ mu,
                  const float* __restrict__ var, u16* __restrict__ out) {
    __shared__ float xs[784];
    __shared__ float wsh[288];
    __shared__ float scl[32], sft[32];
    const int n = blockIdx.x, tid = threadIdx.x;
    for (int i = tid; i < 784; i += 256) xs[i] = x[(size_t)n * 784 + i];
    for (int i = tid; i < 288; i += 256) wsh[i] = w1r[i];
    if (tid < 32) {
        float s = gam[tid] * rsqrtf(var[tid] + BN_EPS);
        scl[tid] = s;
        sft[tid] = (bias[tid] - mu[tid]) * s + bet[tid];
    }
    __syncthreads();
    for (int p = tid; p < 784; p += 256) {
        int y = p / 28, xx = p % 28;
        float patch[9];
#pragma unroll
        for (int dy = 0; dy < 3; ++dy)
#pragma unroll
            for (int dx = 0; dx < 3; ++dx) {
                int gy = y + dy - 1, gx = xx + dx - 1;
                patch[dy * 3 + dx] = (gy >= 0 && gy < 28 && gx >= 0 && gx < 28) ? xs[gy * 28 + gx] : 0.f;
            }
        u32 pk[16];
#pragma unroll
        for (int co = 0; co < 32; co += 2) {
            float s0 = 0.f, s1 = 0.f;
#pragma unroll
            for (int t = 0; t < 9; ++t) {
                s0 += wsh[co * 9 + t] * patch[t];
                s1 += wsh[(co + 1) * 9 + t] * patch[t];
            }
            float v0 = fmaxf(s0 * scl[co] + sft[co], 0.f);
            float v1 = fmaxf(s1 * scl[co + 1] + sft[co + 1], 0.f);
            pk[co >> 1] = ((u32)f2b(v1) << 16) | (u32)f2b(v0);
        }
        size_t base = ((size_t)(n * 30 + y + 1) * 30 + (xx + 1)) * 32;
#pragma unroll
        for (int q = 0; q < 4; ++q) ((uint4*)(out + base))[q] = ((uint4*)pk)[q];
    }
}

// ---------------- conv2: R3-style implicit GEMM, frag-major LDS, fused pool ----------------
template<int CIN, int BN, int HV, int HP, int G, bool POOL, bool PADOUT>
__global__ __launch_bounds__(256)
void convgemm(const u16* __restrict__ act, const u16* __restrict__ bq,
              const float* __restrict__ bias, const float* __restrict__ gam,
              const float* __restrict__ bet, const float* __restrict__ mu,
              const float* __restrict__ var, u16* __restrict__ out) {
    constexpr int BM = 128;
    constexpr int K = 9 * CIN;
    constexpr int S = K / (32 * G);
    constexpr int TPC = CIN / 32;
    constexpr int NT = BN / 32;
    constexpr int RB = BN / 64;
    constexpr int HO = HV / 2;
    constexpr int PP = POOL ? HO * HO : HV * HV;

    __shared__ __align__(16) u16 Alds[G][BM * 32];
    __shared__ __align__(16) u16 Blds[G][BN * 32];
    __shared__ int rowA[BM];
    __shared__ int rowO[BM];
    __shared__ float scl[BN], sft[BN];

    const int tid = threadIdx.x;
    const int m0 = blockIdx.x * BM;

    for (int t = tid; t < BM; t += 256) {
        int base;
        if (POOL) {
            int p = (m0 >> 2) + (t >> 2), q = t & 3;
            int n = p / PP, rr = p % PP;
            int oy = rr / HO, ox = rr % HO;
            int y = oy * 2 + (q >> 1), x = ox * 2 + (q & 1);
            base = ((n * HP + y) * HP + x) * CIN;
        } else {
            int m = m0 + t;
            int n = m / PP, rr = m % PP;
            int y = rr / HV, x = rr % HV;
            base = ((n * HP + y) * HP + x) * CIN;
        }
        rowA[t] = base;
    }
    if (POOL) {
        if (tid < 32) {
            int p = (m0 >> 2) + tid;
            int n = p / PP, rr = p % PP;
            int oy = rr / HO, ox = rr % HO;
            rowO[tid] = PADOUT ? ((n * 16 + oy + 1) * 16 + ox + 1) * BN : p * BN;
        }
    } else {
        for (int t = tid; t < BM; t += 256) {
            int m = m0 + t;
            int n = m / PP, rr = m % PP;
            int y = rr / HV, x = rr % HV;
            rowO[t] = PADOUT ? ((n * 16 + y + 1) * 16 + x + 1) * BN : m * BN;
        }
    }
    if (tid < BN) {
        float s = gam[tid] * rsqrtf(var[tid] + BN_EPS);
        scl[tid] = s;
        sft[tid] = (bias[tid] - mu[tid]) * s + bet[tid];
    }
    __syncthreads();

    int arow[2];
    arow[0] = rowA[(tid >> 6) * 16 + (tid & 15)];
    arow[1] = rowA[64 + (tid >> 6) * 16 + (tid & 15)];
    const int chunkb = ((tid >> 4) & 3) * 16;
    const int bco = (tid >> 6) * 16 + (tid & 15);
    const char* actb = (const char*)act;
    const char* bqb  = (const char*)bq;

    const int wave = tid >> 6, lane = tid & 63;
    const int wm = wave & 1, wn = wave >> 1;
    const int fr16 = lane * 16;

    f32x4 acc[4][NT] = {};

    for (int s = 0; s < S; ++s) {
#pragma unroll
        for (int j = 0; j < G; ++j) {
            int g = s * G + j;
            int tap = g / TPC, cio = (g % TPC) * 32;
            int dy = tap / 3, dx = tap % 3;
            int toffb = ((dy * HP + dx) * CIN + cio) * 2;
            char* Al = (char*)Alds[j];
#pragma unroll
            for (int r = 0; r < 2; ++r)
                load16(actb + (size_t)arow[r] * 2 + toffb + chunkb, Al + r * 4096 + tid * 16);
            char* Bl = (char*)Blds[j];
            int bkob = g * 64 + chunkb;
#pragma unroll
            for (int r = 0; r < RB; ++r)
                load16(bqb + (size_t)(r * 64 + bco) * K * 2 + bkob, Bl + r * 4096 + tid * 16);
        }
        __syncthreads();
#pragma unroll
        for (int j = 0; j < G; ++j) {
            const char* Al = (const char*)Alds[j];
            const char* Bl = (const char*)Blds[j];
            bf16x8 af[4], bf[NT];
#pragma unroll
            for (int mt = 0; mt < 4; ++mt)
                af[mt] = *(const bf16x8*)(Al + (wm * 4 + mt) * 1024 + fr16);
#pragma unroll
            for (int nt = 0; nt < NT; ++nt)
                bf[nt] = *(const bf16x8*)(Bl + (wn * NT + nt) * 1024 + fr16);
#pragma unroll
            for (int mt = 0; mt < 4; ++mt)
#pragma unroll
                for (int nt = 0; nt < NT; ++nt)
                    acc[mt][nt] = __builtin_amdgcn_mfma_f32_16x16x32_bf16(af[mt], bf[nt], acc[mt][nt], 0, 0, 0);
        }
        __syncthreads();
    }

    const int fr = lane & 15, quad = lane >> 4;
    if (POOL) {
#pragma unroll
        for (int mt = 0; mt < 4; ++mt) {
            int pl = wm * 16 + mt * 4 + quad;
            int ob = rowO[pl];
#pragma unroll
            for (int nt = 0; nt < NT; ++nt) {
                int col = wn * (NT * 16) + nt * 16 + fr;
                float sc = scl[col], sh = sft[col];
                f32x4 a = acc[mt][nt];
                float v0 = a[0] * sc + sh, v1 = a[1] * sc + sh;
                float v2 = a[2] * sc + sh, v3 = a[3] * sc + sh;
                float mx = fmaxf(fmaxf(v0, v1), fmaxf(v2, v3));
                out[(size_t)ob + col] = f2b(fmaxf(mx, 0.f));
            }
        }
    } else {
#pragma unroll
        for (int mt = 0; mt < 4; ++mt) {
            int rb = wm * 64 + mt * 16 + quad * 4;
            int o0 = rowO[rb], o1 = rowO[rb + 1], o2 = rowO[rb + 2], o3 = rowO[rb + 3];
#pragma unroll
            for (int nt = 0; nt < NT; ++nt) {
                int col = wn * (NT * 16) + nt * 16 + fr;
                float sc = scl[col], sh = sft[col];
                f32x4 a = acc[mt][nt];
                out[(size_t)o0 + col] = f2b(fmaxf(a[0] * sc + sh, 0.f));
                out[(size_t)o1 + col] = f2b(fmaxf(a[1] * sc + sh, 0.f));
                out[(size_t)o2 + col] = f2b(fmaxf(a[2] * sc + sh, 0.f));
                out[(size_t)o3 + col] = f2b(fmaxf(a[3] * sc + sh, 0.f));
            }
        }
    }
}

// ---------------- conv34 (R7 version, measured 135 us): per-image fused conv3+conv4+pool ----------------
// Block = 1 image, 4 waves (2x2: wm x wn). X2 = act2p tile (32KB, XOR-swizzled)
// staged once; conv3 K-loop barrier-free (A from LDS, B from primed global, L1-hot);
// conv3 out -> swizzled X3 (64KB, aliases X2); conv4 K-loop barrier-free with
// pooled quad-row m-mapping; pool fused in epilogue (f32x4 == 2x2 window).
__global__ __launch_bounds__(256)
void conv34(const u16* __restrict__ act2p, const u16* __restrict__ b3p, const u16* __restrict__ b4p,
            const float* __restrict__ b3, const float* __restrict__ g3, const float* __restrict__ be3,
            const float* __restrict__ m3, const float* __restrict__ v3,
            const float* __restrict__ b4, const float* __restrict__ g4, const float* __restrict__ be4,
            const float* __restrict__ m4, const float* __restrict__ v4,
            u16* __restrict__ out) {
    __shared__ __align__(16) u16 Xs[32768];   // 64KB: X2 in first 32KB, then X3 full

    const int tid = threadIdx.x;
    const int n = blockIdx.x;
    const int wave = tid >> 6, lane = tid & 63;
    const int wm = wave & 1, wn = wave >> 1;
    const int fr = lane & 15, quad = lane >> 4;
    char* X = (char*)Xs;

    // per-lane BN constants (4 cols each layer)
    float scl3[4], sft3[4], scl4[4], sft4[4];
#pragma unroll
    for (int nt = 0; nt < 4; ++nt) {
        int c = wn * 64 + nt * 16 + fr;
        float s = g3[c] * rsqrtf(v3[c] + BN_EPS);
        scl3[nt] = s; sft3[nt] = (b3[c] - m3[c]) * s + be3[c];
        s = g4[c] * rsqrtf(v4[c] + BN_EPS);
        scl4[nt] = s; sft4[nt] = (b4[c] - m4[c]) * s + be4[c];
    }

    // phase A: stage X2 (16x16 x 64ch, row=128B of 8 chunks, chunk pos = c ^ (r&7))
    {
        const uint4* src = (const uint4*)(act2p + (size_t)n * 16384);
#pragma unroll
        for (int it = 0; it < 8; ++it) {
            int i = it * 256 + tid;
            int r = i >> 3, c = i & 7;
            uint4 v = src[i];
            *(uint4*)(X + r * 128 + ((c ^ (r & 7)) * 16)) = v;
        }
    }
    __syncthreads();

    // phase B: conv3, K=576, 18 steps, barrier-free.
    int r0a[7];
#pragma unroll
    for (int mtl = 0; mtl < 7; ++mtl) {
        int g = wm * 7 + mtl + 1;
        int pxc = min(max(fr, 1), 14);
        r0a[mtl] = (g - 1) * 16 + (pxc - 1);
    }
    f32x4 acc[7][4] = {};
    const char* B3 = (const char*)b3p;
#pragma unroll 3
    for (int s = 0; s < 18; ++s) {
        int tap = s >> 1;
        int rdel = (tap / 3) * 16 + tap % 3;
        int cs = (s & 1) * 4;
        bf16x8 af[7], bf[4];
#pragma unroll
        for (int mtl = 0; mtl < 7; ++mtl) {
            int r = r0a[mtl] + rdel;
            int pos = (cs + quad) ^ (r & 7);
            af[mtl] = *(const bf16x8*)(X + r * 128 + pos * 16);
        }
#pragma unroll
        for (int nt = 0; nt < 4; ++nt)
            bf[nt] = *(const bf16x8*)(B3 + ((size_t)((s * 8 + wn * 4 + nt) * 64 + lane)) * 16);
#pragma unroll
        for (int mtl = 0; mtl < 7; ++mtl)
#pragma unroll
            for (int nt = 0; nt < 4; ++nt)
                acc[mtl][nt] = __builtin_amdgcn_mfma_f32_16x16x32_bf16(af[mtl], bf[nt], acc[mtl][nt], 0, 0, 0);
    }
    __syncthreads();   // all X2 reads done; X3 may now overwrite

    // phase C: build X3 (16x16 x 128ch, row=256B of 16 chunks, pos = c ^ (r&15)),
    // borders zero, interior = BN+ReLU(conv3) as bf16
    for (int t = tid; t < 60 * 16; t += 256) {
        int j = t & 15, b = t >> 4;
        int m = (b < 16) ? b : (b < 32) ? 240 + (b - 16) : (b < 46) ? (b - 31) * 16 : (b - 45) * 16 + 15;
        *(uint4*)(X + m * 256 + j * 16) = make_uint4(0, 0, 0, 0);
    }
#pragma unroll
    for (int mtl = 0; mtl < 7; ++mtl) {
        int g = wm * 7 + mtl + 1;
#pragma unroll
        for (int nt = 0; nt < 4; ++nt) {
            int col = wn * 64 + nt * 16 + fr;
            int c = col >> 3;
            f32x4 a = acc[mtl][nt];
#pragma unroll
            for (int j = 0; j < 4; ++j) {
                int px = quad * 4 + j;
                if (px >= 1 && px <= 14) {
                    int m = g * 16 + px;
                    float v = fmaxf(a[j] * scl3[nt] + sft3[nt], 0.f);
                    *(u16*)(X + m * 256 + ((c ^ (m & 15)) * 16) + (col & 7) * 2) = f2b(v);
                }
            }
        }
    }
    __syncthreads();

    // phase D: conv4, K=1152, 36 steps, barrier-free; pool fused (m = p*4+q)
    int r0b[7];
#pragma unroll
    for (int mtl = 0; mtl < 7; ++mtl) {
        int m = (wm * 7 + mtl) * 16 + fr;
        int p = min(m >> 2, 48), q = m & 3;
        int y2 = (p / 7) * 2 + (q >> 1), x2 = (p % 7) * 2 + (q & 1);
        r0b[mtl] = y2 * 16 + x2;
    }
    f32x4 acc4[7][4] = {};
    const char* B4 = (const char*)b4p;
#pragma unroll 2
    for (int s = 0; s < 36; ++s) {
        int tap = s >> 2;
        int rdel = (tap / 3) * 16 + tap % 3;
        int cs = (s & 3) * 4;
        bf16x8 af[7], bf[4];
#pragma unroll
        for (int mtl = 0; mtl < 7; ++mtl) {
            int r = r0b[mtl] + rdel;
            int pos = (cs + quad) ^ (r & 15);
            af[mtl] = *(const bf16x8*)(X + r * 256 + pos * 16);
        }
#pragma unroll
        for (int nt = 0; nt < 4; ++nt)
            bf[nt] = *(const bf16x8*)(B4 + ((size_t)((s * 8 + wn * 4 + nt) * 64 + lane)) * 16);
#pragma unroll
        for (int mtl = 0; mtl < 7; ++mtl)
#pragma unroll
            for (int nt = 0; nt < 4; ++nt)
                acc4[mtl][nt] = __builtin_amdgcn_mfma_f32_16x16x32_bf16(af[mtl], bf[nt], acc4[mtl][nt], 0, 0, 0);
    }
    // epilogue: f32x4 = one 2x2 pool window (rows p*4..p*4+3)
#pragma unroll
    for (int mtl = 0; mtl < 7; ++mtl) {
        int p = (wm * 7 + mtl) * 4 + quad;
        if (p < 49) {
#pragma unroll
            for (int nt = 0; nt < 4; ++nt) {
                int col = wn * 64 + nt * 16 + fr;
                f32x4 a = acc4[mtl][nt];
                float v0 = a[0] * scl4[nt] + sft4[nt];
                float v1 = a[1] * scl4[nt] + sft4[nt];
                float v2 = a[2] * scl4[nt] + sft4[nt];
                float v3 = a[3] * scl4[nt] + sft4[nt];
                float mx = fmaxf(fmaxf(v0, v1), fmaxf(v2, v3));
                out[((size_t)n * 49 + p) * 128 + col] = f2b(fmaxf(mx, 0.f));
            }
        }
    }
}

// ---------------- fc1: split-K MFMA GEMM (LDS dbuf), atomicAdd f32 into f1 ----------------
__global__ __launch_bounds__(256)
void fc1gemm(const u16* __restrict__ A, const u16* __restrict__ Bq, float* __restrict__ out) {
    constexpr int K = 6272, KC = 896, S = KC / 64;
    __shared__ __align__(16) u16 Alds[2][128 * 32];
    __shared__ __align__(16) u16 Blds[2][128 * 32];
    const int tid = threadIdx.x;
    const int m0 = blockIdx.x * 128;
    const int n0 = blockIdx.y * 128;
    const int k0 = blockIdx.z * KC;
    const int chunkb = ((tid >> 4) & 3) * 16;
    const int rr = (tid >> 6) * 16 + (tid & 15);
    const char* Ag = (const char*)A;
    const char* Bg = (const char*)Bq;
    const int wave = tid >> 6, lane = tid & 63;
    const int wm = wave & 1, wn = wave >> 1;
    const int fr16 = lane * 16;
    f32x4 acc[4][4] = {};

    for (int s = 0; s < S; ++s) {
#pragma unroll
        for (int j = 0; j < 2; ++j) {
            int kb = (k0 + s * 64 + j * 32) * 2 + chunkb;
            char* Al = (char*)Alds[j];
            char* Bl = (char*)Blds[j];
#pragma unroll
            for (int r = 0; r < 2; ++r) {
                load16(Ag + (size_t)(m0 + r * 64 + rr) * K * 2 + kb, Al + r * 4096 + tid * 16);
                load16(Bg + (size_t)(n0 + r * 64 + rr) * K * 2 + kb, Bl + r * 4096 + tid * 16);
            }
        }
        __syncthreads();
#pragma unroll
        for (int j = 0; j < 2; ++j) {
            const char* Al = (const char*)Alds[j];
            const char* Bl = (const char*)Blds[j];
            bf16x8 af[4], bf[4];
#pragma unroll
            for (int mt = 0; mt < 4; ++mt)
                af[mt] = *(const bf16x8*)(Al + (wm * 4 + mt) * 1024 + fr16);
#pragma unroll
            for (int nt = 0; nt < 4; ++nt)
                bf[nt] = *(const bf16x8*)(Bl + (wn * 4 + nt) * 1024 + fr16);
#pragma unroll
            for (int mt = 0; mt < 4; ++mt)
#pragma unroll
                for (int nt = 0; nt < 4; ++nt)
                    acc[mt][nt] = __builtin_amdgcn_mfma_f32_16x16x32_bf16(af[mt], bf[nt], acc[mt][nt], 0, 0, 0);
        }
        __syncthreads();
    }
    const int fr = lane & 15, quad = lane >> 4;
#pragma unroll
    for (int mt = 0; mt < 4; ++mt) {
        int row = m0 + wm * 64 + mt * 16 + quad * 4;
#pragma unroll
        for (int nt = 0; nt < 4; ++nt) {
            int col = n0 + wn * 64 + nt * 16 + fr;
            f32x4 a = acc[mt][nt];
            atomicAdd(&out[(size_t)(row + 0) * 256 + col], a[0]);
            atomicAdd(&out[(size_t)(row + 1) * 256 + col], a[1]);
            atomicAdd(&out[(size_t)(row + 2) * 256 + col], a[2]);
            atomicAdd(&out[(size_t)(row + 3) * 256 + col], a[3]);
        }
    }
}

// ---------------- fc2 fp32 GEMM; applies fc1's BN+ReLU to A on load ----------------
__global__ __launch_bounds__(256)
void fc2_kernel(const float* __restrict__ A, const float* __restrict__ Bw,
                const float* __restrict__ bA, const float* __restrict__ gA,
                const float* __restrict__ beA, const float* __restrict__ mA,
                const float* __restrict__ vA,
                const float* __restrict__ bias, const float* __restrict__ gam,
                const float* __restrict__ bet, const float* __restrict__ mu,
                const float* __restrict__ var, float* __restrict__ out) {
    constexpr int Nn = 128, K = 256;
    __shared__ __align__(16) float As[16][68];
    __shared__ __align__(16) float Bs[16][68];
    __shared__ float sclA[256], sftA[256];
    const int tid = threadIdx.x;
    const int n0 = blockIdx.x * 64, m0 = blockIdx.y * 64;
    if (tid < 256) {
        float s = gA[tid] * rsqrtf(vA[tid] + BN_EPS);
        sclA[tid] = s;
        sftA[tid] = (bA[tid] - mA[tid]) * s + beA[tid];
    }
    const int tm = tid >> 4, tn = tid & 15;
    const int lr = tid >> 2, lk = (tid & 3) * 4;
    float acc[4][4] = {};
    __syncthreads();
    for (int k0 = 0; k0 < K; k0 += 16) {
        float4 av = *(const float4*)&A[(size_t)(m0 + lr) * K + k0 + lk];
        float4 bv = *(const float4*)&Bw[(size_t)(n0 + lr) * K + k0 + lk];
        As[lk + 0][lr] = fmaxf(av.x * sclA[k0 + lk + 0] + sftA[k0 + lk + 0], 0.f);
        As[lk + 1][lr] = fmaxf(av.y * sclA[k0 + lk + 1] + sftA[k0 + lk + 1], 0.f);
        As[lk + 2][lr] = fmaxf(av.z * sclA[k0 + lk + 2] + sftA[k0 + lk + 2], 0.f);
        As[lk + 3][lr] = fmaxf(av.w * sclA[k0 + lk + 3] + sftA[k0 + lk + 3], 0.f);
        Bs[lk + 0][lr] = bv.x; Bs[lk + 1][lr] = bv.y; Bs[lk + 2][lr] = bv.z; Bs[lk + 3][lr] = bv.w;
        __syncthreads();
#pragma unroll
        for (int k = 0; k < 16; ++k) {
            float4 a = *(const float4*)&As[k][tm * 4];
            float4 b = *(const float4*)&Bs[k][tn * 4];
            acc[0][0] += a.x * b.x; acc[0][1] += a.x * b.y; acc[0][2] += a.x * b.z; acc[0][3] += a.x * b.w;
            acc[1][0] += a.y * b.x; acc[1][1] += a.y * b.y; acc[1][2] += a.y * b.z; acc[1][3] += a.y * b.w;
            acc[2][0] += a.z * b.x; acc[2][1] += a.z * b.y; acc[2][2] += a.z * b.z; acc[2][3] += a.z * b.w;
            acc[3][0] += a.w * b.x; acc[3][1] += a.w * b.y; acc[3][2] += a.w * b.z; acc[3][3] += a.w * b.w;
        }
        __syncthreads();
    }
#pragma unroll
    for (int i = 0; i < 4; ++i) {
        int row = m0 + tm * 4 + i;
#pragma unroll
        for (int j = 0; j < 4; ++j) {
            int col = n0 + tn * 4 + j;
            float sc = gam[col] * rsqrtf(var[col] + BN_EPS);
            float v = (acc[i][j] + bias[col] - mu[col]) * sc + bet[col];
            out[(size_t)row * Nn + col] = fmaxf(v, 0.f);
        }
    }
}

__global__ __launch_bounds__(256)
void fc3_kernel(const float* __restrict__ A, const float* __restrict__ Bw,
                const float* __restrict__ bias, float* __restrict__ out) {
    int i = blockIdx.x * blockDim.x + threadIdx.x;
    if (i >= 1024 * 10) return;
    int n = i / 10, j = i % 10;
    const float4* a = (const float4*)&A[(size_t)n * 128];
    const float4* b = (const float4*)&Bw[(size_t)j * 128];
    float s = 0.f;
#pragma unroll
    for (int k = 0; k < 32; ++k) {
        float4 x = a[k], y = b[k];
        s += x.x * y.x + x.y * y.y + x.z * y.z + x.w * y.w;
    }
    out[i] = s + bias[j];
}

extern "C" void kernel_launch(void* const* d_in, const int* in_sizes, int n_in,
                              void* d_out, int out_size, void* d_ws, size_t ws_size,
                              hipStream_t stream) {
    (void)in_sizes; (void)n_in; (void)out_size; (void)ws_size;
    const float* x   = (const float*)d_in[0];
    const float* w1  = (const float*)d_in[1];
    const float* w2  = (const float*)d_in[2];
    const float* w3  = (const float*)d_in[3];
    const float* w4  = (const float*)d_in[4];
    const float* wf1 = (const float*)d_in[5];
    const float* wf2 = (const float*)d_in[6];
    const float* wf3 = (const float*)d_in[7];
    auto P = [&](int i) { return (const float*)d_in[i]; };
    char* wsb = (char*)d_ws;
    float* sums = (float*)(wsb + O_SUMS);
    float* w1r  = (float*)(wsb + O_W1R);
    float* wf2q = (float*)(wsb + O_WF2Q);
    float* wf3q = (float*)(wsb + O_WF3Q);
    u16* bq2   = (u16*)(wsb + O_BQ2);
    u16* bq3p  = (u16*)(wsb + O_BQ3);
    u16* bq4p  = (u16*)(wsb + O_BQ4);
    u16* bqf1  = (u16*)(wsb + O_BQF1);
    float* f1  = (float*)(wsb + O_F1);
    float* f2  = (float*)(wsb + O_F2);
    u16* act1  = (u16*)(wsb + O_ACT1);
    u16* act2p = (u16*)(wsb + O_ACT2);
    u16* act4p = (u16*)(wsb + O_ACT4);

    // ternarization: 3 launches
    zero_sums<<<1, 64, 0, stream>>>(sums);
    absmean_all<<<226, 256, 0, stream>>>(w1, w2, w3, w4, wf1, wf2, wf3, sums);
    tern_all<<<634, 256, 0, stream>>>(w1, w2, w3, w4, wf1, wf2, wf3, sums,
                                      w1r, bq2, bq3p, bq4p, bqf1, wf2q, wf3q);

    // merged border zeros + f1 zero (one launch)
    init_bufs<<<4032, 256, 0, stream>>>(act1, act2p, f1);

    // conv1 -> act1 (pad30 interior)
    conv1_direct<<<1024, 256, 0, stream>>>(x, w1r, P(8), P(9), P(10), P(11), P(12), act1);
    // conv2 + fused pool -> act2p (pad16 C=64 interior)
    convgemm<32, 64, 28, 30, 1, true, true><<<6272, 256, 0, stream>>>(
        act1, bq2, P(13), P(14), P(15), P(16), P(17), act2p);
    // fused conv3+conv4+pool -> act4p [1024*49][128]
    conv34<<<1024, 256, 0, stream>>>(
        act2p, bq3p, bq4p,
        P(18), P(19), P(20), P(21), P(22),
        P(23), P(24), P(25), P(26), P(27), act4p);
    // fc1 split-K (7 chunks of 896) -> atomic f32 into f1
    fc1gemm<<<dim3(8, 2, 7), 256, 0, stream>>>(act4p, bqf1, f1);
    // fc2 (applies fc1 BN+ReLU on A-load) -> f2
    fc2_kernel<<<dim3(2, 16), 256, 0, stream>>>(
        f1, wf2q, P(28), P(29), P(30), P(31), P(32),
        P(33), P(34), P(35), P(36), P(37), f2);
    // fc3 -> logits
    fc3_kernel<<<40, 256, 0, stream>>>(f2, wf3q, P(38), (float*)d_out);
}